// Round 13
// baseline (493.751 us; speedup 1.0000x reference)
//
#include <hip/hip_runtime.h>
#include <hip/hip_bf16.h>
#include <hip/hip_cooperative_groups.h>
#include <stdint.h>

#define NN 4096

namespace cg = cooperative_groups;

// Round-33: R11 config (proven 249.2 us) + layers fused via
// hipLaunchCooperativeKernel with cg::this_grid().sync() — the sanctioned
// grid barrier with correct cross-XCD memory semantics (R12's hand-rolled
// relaxed-load spin read stale L1 and burned ~250 us). Dispatches 7 -> 5.
// scan/cra2/a4row identical to round-31 best.

__device__ __forceinline__ unsigned int wave_umax_bcast(unsigned int v) {
    // full-wave64 max on the VALU via DPP; result broadcast via readlane.
    int x = (int)v;                           // values <= ~65k: signed==unsigned
    x = max(x, __builtin_amdgcn_update_dpp(0, x, 0x111, 0xF, 0xF, true)); // row_shr:1
    x = max(x, __builtin_amdgcn_update_dpp(0, x, 0x112, 0xF, 0xF, true)); // row_shr:2
    x = max(x, __builtin_amdgcn_update_dpp(0, x, 0x114, 0xF, 0xF, true)); // row_shr:4
    x = max(x, __builtin_amdgcn_update_dpp(0, x, 0x118, 0xF, 0xF, true)); // row_shr:8
    x = max(x, __builtin_amdgcn_update_dpp(0, x, 0x142, 0xF, 0xF, true)); // row_bcast:15
    x = max(x, __builtin_amdgcn_update_dpp(0, x, 0x143, 0xF, 0xF, true)); // row_bcast:31
    return (unsigned int)__builtin_amdgcn_readlane(x, 63);
}

// ---------------------------------------------------------------------------
// K1: scan_k — one pass over adj per row with float4 loads (16 B/lane).
// Bit layout of abits: word(e) = ((e>>8)<<2)|(e&3), bit(e) = (e>>2)&63.
// ---------------------------------------------------------------------------
__global__ __launch_bounds__(256) void scan_k(const float* __restrict__ adj,
                                              int* __restrict__ nbr,
                                              int* __restrict__ deg,
                                              unsigned long long* __restrict__ abits,
                                              float* __restrict__ feats) {
    __shared__ int nlist[4][64];
    int tid = threadIdx.x;
    int wv = tid >> 6, ln = tid & 63;
    int v = blockIdx.x * 4 + wv;
    size_t rb = (size_t)v * NN;
    int total = 0;
    unsigned long long w0 = 0;
    const float4* row4 = (const float4*)(adj + rb);
    for (int base = 0; base < NN; base += 256) {
        float4 f = row4[(base >> 2) + ln];
        int q4 = (base >> 8) << 2;
        #pragma unroll
        for (int j = 0; j < 4; j++) {
            float vj = (j == 0) ? f.x : (j == 1) ? f.y : (j == 2) ? f.z : f.w;
            unsigned long long m = __ballot(vj > 0.5f);
            if (vj > 0.5f) {
                int pos = total + __popcll(m & ((1ull << ln) - 1ull));
                if (pos < 64) nlist[wv][pos] = base + 4 * ln + j;
            }
            if (ln == q4 + j) w0 = m;
            total += __popcll(m);
        }
    }
    abits[(size_t)v * 64 + ln] = w0;
    int degL = min(total, 64);
    if (ln < degL) nbr[v * 64 + ln] = nlist[wv][ln];
    if (ln == 0) {
        deg[v] = total;
        float degf = (float)total;
        feats[v * 16 + 12] = degf;
        feats[v * 16 + 13] = degf * degf;
        feats[v * 16 + 14] = degf;           // diag(A^2) = deg (symmetric 0/1)
    }
}

// ---------------------------------------------------------------------------
// K2: cra2_k — role-split merged dispatch:
//   blocks [0, 4096):    pair-list -> a3 (LDS, 2-src weight-1 scatter)
//                        -> STRIDED nibble row + overflow side-list
//   blocks [4096, 5120): cr_feat from the L2-resident bitmask (4 nodes/block)
// ---------------------------------------------------------------------------
__global__ __launch_bounds__(256) void cra2_k(const unsigned long long* __restrict__ abits,
                                              const int* __restrict__ nbr,
                                              const int* __restrict__ deg,
                                              unsigned int* __restrict__ a3n,
                                              unsigned int* __restrict__ side,
                                              unsigned int* __restrict__ scnt,
                                              float* __restrict__ feats) {
    __shared__ __align__(64) unsigned int smem[NN + 196 + 640];
    int tid = threadIdx.x;
    int bid = blockIdx.x;
    int wv = tid >> 6, ln = tid & 63;

    if (bid < NN) {
        // ------------------- a3 role (pair-expanded) -------------------
        unsigned int* acc   = smem;                     // [4096]
        int* us             = (int*)(smem + NN);        // [64]
        int* dus            = (int*)(smem + NN + 64);   // [64]
        unsigned int* pbase = smem + NN + 128;          // [64] excl prefix of dus
        unsigned int* wsumS = smem + NN + 192;          // [4]
        unsigned int* plist = smem + NN + 196;          // [640] (dgw<<12)|w
        int v = bid;
        uint4 z = {0u, 0u, 0u, 0u};
        #pragma unroll
        for (int i = 0; i < 4; i++) ((uint4*)acc)[tid + 256 * i] = z;
        int dv = min(deg[v], 64);
        if (tid < 64) {
            int u = (tid < dv) ? nbr[v * 64 + tid] : 0;
            us[tid] = u;
            int du = (tid < dv) ? min(deg[u], 64) : 0;
            dus[tid] = du;
            // exclusive prefix of dus across wave 0
            int incl = du;
            #pragma unroll
            for (int off = 1; off < 64; off <<= 1) {
                int n = __shfl_up(incl, off, 64);
                if (tid >= off) incl += n;
            }
            pbase[tid] = (unsigned int)(incl - du);
            if (tid == 63) wsumS[0] = (unsigned int)incl;   // total pair count
        }
        __syncthreads();
        int npair = (int)min(wsumS[0], 640u);
        // fill pair list: entry = w | (min(deg[w],64)<<12); direct writes
        for (int p = tid; p < dv * 64; p += 256) {
            int i = p >> 6, j = p & 63;
            if (j < dus[i]) {
                unsigned int pos = pbase[i] + (unsigned int)j;
                if (pos < 640u) {
                    unsigned int w = (unsigned int)nbr[us[i] * 64 + j];
                    plist[pos] = w | ((unsigned int)min(deg[w], 64) << 12);
                }
            }
        }
        __syncthreads();
        // a3 scatter: acc[x] = sum over pairs (u,w) of A[w,x]; weight == 1.
        int lim64 = ((npair + 1) >> 1) << 6;
        for (int q = tid; q < lim64; q += 256) {
            int s = ((q >> 6) << 1) | ((q >> 5) & 1);
            int j = q & 31;
            if (s < npair) {
                unsigned int e = plist[s];
                int dgw = (int)(e >> 12);
                const int* nrw = nbr + (e & 0xFFFu) * 64;
                if (j < dgw) atomicAdd(&acc[nrw[j]], 1u);
                if (j == 31) {
                    for (int jj = 32; jj < dgw; jj++) atomicAdd(&acc[nrw[jj]], 1u);
                }
            }
        }
        __syncthreads();
        // STRIDED nibble emit (word w = cols {w+512k}) + overflow side-list.
        unsigned int wA = 0, wB = 0, ovm = 0;
        #pragma unroll
        for (int k = 0; k < 8; k++) {
            unsigned int a = acc[tid + 512 * k];
            wA |= min(a, 15u) << (4 * k);
            ovm |= (a > 15u ? 1u : 0u) << k;
        }
        #pragma unroll
        for (int k = 0; k < 8; k++) {
            unsigned int a = acc[tid + 256 + 512 * k];
            wB |= min(a, 15u) << (4 * k);
            ovm |= (a > 15u ? 1u : 0u) << (8 + k);
        }
        a3n[(size_t)v * 512 + tid] = wA;
        a3n[(size_t)v * 512 + tid + 256] = wB;
        int lov = __popc(ovm);
        int inc2 = lov;
        #pragma unroll
        for (int off = 1; off < 64; off <<= 1) {
            int n = __shfl_up(inc2, off, 64);
            if (ln >= off) inc2 += n;
        }
        if (ln == 63) wsumS[wv] = (unsigned int)inc2;
        __syncthreads();
        unsigned int wpre2 = 0, totS = 0;
        #pragma unroll
        for (int q = 0; q < 4; q++) {
            unsigned int s = wsumS[q];
            if (q < wv) wpre2 += s;
            totS += s;
        }
        unsigned int pos2 = wpre2 + (unsigned int)(inc2 - lov);
        unsigned int* sideR = side + (size_t)v * 192;
        while (ovm) {
            int i2 = __ffs(ovm) - 1;
            ovm &= ovm - 1;
            unsigned int col = (i2 < 8) ? (unsigned int)(tid + 512 * i2)
                                        : (unsigned int)(tid + 256 + 512 * (i2 - 8));
            unsigned int a = acc[col];
            if (pos2 < 192u) sideR[pos2] = ((a - 15u) << 16) | col;
            pos2++;
        }
        if (tid == 0) scnt[v] = min(totS, 192u);
    } else {
        // ------------------- cr role -------------------
        unsigned long long* rows = (unsigned long long*)smem;   // [4][64], 2 KB
        int* mems = (int*)(smem + 1024);                        // [4][64], 1 KB
        int v = (bid - NN) * 4 + wv;

        int dv = deg[v];
        int degL = min(dv, 64);
        int c = min(dv + 1, 64);

        int nl = (ln < degL) ? nbr[v * 64 + ln] : 0;
        int isless = (ln < degL && nl < v) ? 1 : 0;
        int pos = isless;
        #pragma unroll
        for (int off = 32; off; off >>= 1) pos += __shfl_xor(pos, off, 64);

        int mem = 0;
        if (ln < c) {
            if (ln < pos)       mem = nl;
            else if (ln == pos) mem = v;
            else                mem = nbr[v * 64 + ln - 1];
        }
        mems[wv * 64 + ln] = mem;
        __syncthreads();

        unsigned long long mask = 0ull;
        {
            const unsigned long long* rowb = abits + (size_t)mem * 64;
            for (int j = 0; j < c; j++) {
                int mj = mems[wv * 64 + j];
                unsigned long long w = rowb[((mj >> 8) << 2) | (mj & 3)];
                mask |= ((w >> ((mj >> 2) & 63)) & 1ull) << j;
            }
        }
        if (ln >= c) mask = 0ull;
        rows[wv * 64 + ln] = mask;
        __syncthreads();

        int tpart = 0;
        float epart = 0.f, wpart = 0.f;
        if (ln < c) {
            unsigned long long mm = mask;
            while (mm) {
                int j = __ffsll(mm) - 1;
                mm &= mm - 1;
                tpart += __popcll(mask & rows[wv * 64 + j]);
            }
            if (ln != pos) {
                int cn = __popcll(rows[wv * 64 + pos] & mask);
                float D2 = (float)cn + 1.0f;
                epart = D2;
                wpart = D2 * (D2 - 1.0f) * 0.5f;
            }
        }
        float es = epart, wsum2 = wpart;
        int ts = tpart;
        #pragma unroll
        for (int off = 32; off; off >>= 1) {
            es += __shfl_xor(es, off, 64);
            wsum2 += __shfl_xor(wsum2, off, 64);
            ts += __shfl_xor(ts, off, 64);
        }

        if (ln == 0) {
            float degf = (float)dv;
            float k = degf + 1.0f;
            float E = 0.5f * (es + degf);
            float W = wsum2 + degf * (degf - 1.0f) * 0.5f;
            float T = (float)ts / 6.0f;
            float f3 = T;
            float f2 = W - 3.0f * T;
            float f1 = E * (k - 2.0f) - 2.0f * f2 - 3.0f * f3;
            float tot2 = k * (k - 1.0f) * (k - 2.0f) / 6.0f;
            float f0 = tot2 - f1 - f2 - f3;
            if (k < 3.0f) { f0 = f1 = f2 = f3 = 0.f; }
            float s = f0 + f1 + f2 + f3 + 1e-10f;
            feats[v * 16 + 0] = f0 / s;
            feats[v * 16 + 1] = f1 / s;
            feats[v * 16 + 2] = f2 / s;
            feats[v * 16 + 3] = f3 / s;
        }
    }
}

// ---------------------------------------------------------------------------
// K4: fused a4-row (register-gather over strided nibble a3 + side-list) +
// top-8 + embedding. Max-reduces on VALU DPP.
// ---------------------------------------------------------------------------
__global__ __launch_bounds__(512) void a4row_k(const unsigned int* __restrict__ a3n,
                                               const unsigned int* __restrict__ side,
                                               const unsigned int* __restrict__ scnt,
                                               const int* __restrict__ deg,
                                               const int* __restrict__ nbr,
                                               const float* __restrict__ feats,
                                               const float* __restrict__ e_w,
                                               const float* __restrict__ e_b,
                                               float* __restrict__ x0) {
    __shared__ unsigned int sacc[NN];        // 16 KB u32 side accumulator
    __shared__ unsigned int sbase[64];       // u*512 (word base of a3 row)
    __shared__ unsigned int sbs[64];         // u*192 (side base)
    __shared__ unsigned int sS[64];          // side counts
    __shared__ unsigned int wtops[64];
    int tid = threadIdx.x;
    int wv = tid >> 6, ln = tid & 63;
    int v = blockIdx.x;

    {
        uint4 z = {0u, 0u, 0u, 0u};
        ((uint4*)sacc)[tid] = z;
        ((uint4*)sacc)[tid + 512] = z;
    }
    int dvv = min(deg[v], 64);
    if (tid < dvv) {
        unsigned int u = (unsigned int)nbr[v * 64 + tid];
        sbase[tid] = u * 512u;
        sbs[tid]   = u * 192u;
        sS[tid]    = scnt[u];
    }
    __syncthreads();

    // side scatter (few hundred entries; hides under the base loop)
    for (int i = wv; i < dvv; i += 8) {
        int ns = (int)sS[i];
        const unsigned int* sp = side + sbs[i];
        for (int g2 = ln; g2 < ns; g2 += 64) {
            unsigned int e = sp[g2];
            atomicAdd(&sacc[e & 0xFFFu], e >> 16);
        }
    }

    // base: register gather-accumulate (owner-columns, strided layout)
    unsigned int aE = 0, aO = 0;
    unsigned int SE0 = 0, SE1 = 0, SO0 = 0, SO1 = 0;
    for (int s0 = 0; s0 < dvv; s0 += 16) {
        int se = min(s0 + 16, dvv);
        for (int s = s0; s < se; s++) {
            unsigned int w = a3n[sbase[s] + (unsigned int)tid];
            aE += w & 0x0F0F0F0Fu;
            aO += (w >> 4) & 0x0F0F0F0Fu;
        }
        SE0 += __builtin_amdgcn_perm(0u, aE, 0x0c010c00u);   // {aE.b0, aE.b1} u16
        SE1 += __builtin_amdgcn_perm(0u, aE, 0x0c030c02u);   // {aE.b2, aE.b3}
        SO0 += __builtin_amdgcn_perm(0u, aO, 0x0c010c00u);
        SO1 += __builtin_amdgcn_perm(0u, aO, 0x0c030c02u);
        aE = 0; aO = 0;
    }
    __syncthreads();

    // merge side sums with register base sums (strided col map).
    unsigned int vv[8];
    vv[0] = (SE0 & 0xFFFFu) + sacc[tid];
    vv[1] = (SO0 & 0xFFFFu) + sacc[tid + 512];
    vv[2] = (SE0 >> 16)     + sacc[tid + 1024];
    vv[3] = (SO0 >> 16)     + sacc[tid + 1536];
    vv[4] = (SE1 & 0xFFFFu) + sacc[tid + 2048];
    vv[5] = (SO1 & 0xFFFFu) + sacc[tid + 2560];
    vv[6] = (SE1 >> 16)     + sacc[tid + 3072];
    vv[7] = (SO1 >> 16)     + sacc[tid + 3584];

    // per-thread top-8 over the 8 owned columns
    unsigned int best[8];
    #pragma unroll
    for (int q = 0; q < 8; q++) best[q] = 0u;
    #pragma unroll
    for (int m = 0; m < 8; m++) {
        unsigned int val = vv[m];
        if (val > best[7]) {
            best[7] = val;
            #pragma unroll
            for (int s = 7; s > 0; s--) {
                if (best[s] > best[s - 1]) {
                    unsigned int t2 = best[s - 1]; best[s - 1] = best[s]; best[s] = t2;
                } else break;
            }
        }
    }

    // per-wave extract of 8 maxima (DPP max-reduce, VALU-only)
    unsigned int wave_val = 0u;
    #pragma unroll
    for (int r = 0; r < 8; r++) {
        unsigned int m = wave_umax_bcast(best[0]);
        unsigned long long bb = __ballot(best[0] == m);
        int src = __ffsll(bb) - 1;
        if (ln == src) {
            #pragma unroll
            for (int s = 0; s < 7; s++) best[s] = best[s + 1];
            best[7] = 0u;
        }
        if (ln == r) wave_val = m;
    }
    if (ln < 8) wtops[wv * 8 + ln] = wave_val;
    __syncthreads();

    // wave 0: merge 64 candidates, then fused embedding
    if (wv == 0) {
        unsigned int cand = wtops[ln];
        unsigned int myv = 0u;
        #pragma unroll
        for (int r = 0; r < 8; r++) {
            unsigned int m = wave_umax_bcast(cand);
            unsigned long long bb = __ballot(cand == m);
            int src = __ffsll(bb) - 1;
            if (ln == src) cand = 0u;
            if (ln == r) myv = m;
        }
        int d = ln;
        float s = e_b[d];
        s += feats[v * 16 + 0]  * e_w[0 * 64 + d];
        s += feats[v * 16 + 1]  * e_w[1 * 64 + d];
        s += feats[v * 16 + 2]  * e_w[2 * 64 + d];
        s += feats[v * 16 + 3]  * e_w[3 * 64 + d];
        #pragma unroll
        for (int j = 0; j < 8; j++) {
            float mj = (float)(unsigned int)__shfl((int)myv, j, 64);
            s += mj * e_w[(4 + j) * 64 + d];
        }
        s += feats[v * 16 + 12] * e_w[12 * 64 + d];
        s += feats[v * 16 + 13] * e_w[13 * 64 + d];
        s += feats[v * 16 + 14] * e_w[14 * 64 + d];
        x0[(size_t)v * 64 + d] = s;
    }
}

// ---------------------------------------------------------------------------
// K5: layers_k — all 3 GNN layers in one COOPERATIVE kernel; grid-wide sync
// via cg::this_grid().sync() (correct cross-XCD semantics). 1024 blocks x
// 256 threads @ 4 blocks/CU — well within co-residency. Same per-layer math
// and summation order as the old layer_k -> bit-identical output.
// ---------------------------------------------------------------------------
__global__ __launch_bounds__(256, 4) void layers_k(float* __restrict__ x0,
                                                   float* __restrict__ x1,
                                                   const float* __restrict__ w1,
                                                   const float* __restrict__ b1,
                                                   const float* __restrict__ w2,
                                                   const float* __restrict__ b2,
                                                   const float* __restrict__ eps,
                                                   const int* __restrict__ nbr,
                                                   const int* __restrict__ deg,
                                                   float* __restrict__ out) {
    cg::grid_group grid = cg::this_grid();
    __shared__ float wL[4096];                // 16 KB, reused for w1 then w2
    __shared__ float h[4][64], t[4][64];
    int tid = threadIdx.x;
    int wv = tid >> 6, d = tid & 63;
    int v = blockIdx.x * 4 + wv;

    int dv = min(deg[v], 64);
    const int* nl = nbr + v * 64;

    #pragma unroll 1
    for (int li = 0; li < 3; li++) {
        const float* xin = (li == 1) ? x1 : x0;
        float* xout = (li == 0) ? x1 : x0;

        // stage w1 (coalesced float4)
        {
            const float4* src = (const float4*)(w1 + li * 4096);
            #pragma unroll
            for (int i = 0; i < 4; i++) ((float4*)wL)[tid + 256 * i] = src[tid + 256 * i];
        }

        float xv = xin[(size_t)v * 64 + d];
        float agg = 0.f;
        int j = 0;
        for (; j + 4 <= dv; j += 4) {
            int n0 = nl[j], n1 = nl[j + 1], n2 = nl[j + 2], n3 = nl[j + 3];
            float a0 = xin[(size_t)n0 * 64 + d];
            float a1 = xin[(size_t)n1 * 64 + d];
            float a2v = xin[(size_t)n2 * 64 + d];
            float a3 = xin[(size_t)n3 * 64 + d];
            agg += (a0 + a1) + (a2v + a3);
        }
        for (; j < dv; j++) agg += xin[(size_t)nl[j] * 64 + d];
        float hv = (1.0f + eps[li]) * xv + agg;
        h[wv][d] = hv;
        __syncthreads();

        float s = b1[li * 64 + d];
        #pragma unroll 8
        for (int k = 0; k < 64; k++) s += h[wv][k] * wL[k * 64 + d];
        s = fmaxf(s, 0.f);
        t[wv][d] = s;
        __syncthreads();

        // stage w2 (reuse wL)
        {
            const float4* src = (const float4*)(w2 + li * 4096);
            #pragma unroll
            for (int i = 0; i < 4; i++) ((float4*)wL)[tid + 256 * i] = src[tid + 256 * i];
        }
        __syncthreads();

        float o = b2[li * 64 + d];
        #pragma unroll 8
        for (int k = 0; k < 64; k++) o += t[wv][k] * wL[k * 64 + d];

        if (li == 2) {
            h[wv][d] = o;
            __syncthreads();
            if (wv == 0)
                atomicAdd(&out[d], (h[0][d] + h[1][d]) + (h[2][d] + h[3][d]));
        } else {
            xout[(size_t)v * 64 + d] = o;
            grid.sync();
        }
    }
}

// ---------------------------------------------------------------------------
extern "C" void kernel_launch(void* const* d_in, const int* in_sizes, int n_in,
                              void* d_out, int out_size, void* d_ws, size_t ws_size,
                              hipStream_t stream) {
    const float* adj = (const float*)d_in[0];
    const float* e_w = (const float*)d_in[1];
    const float* e_b = (const float*)d_in[2];
    const float* w1  = (const float*)d_in[3];
    const float* b1  = (const float*)d_in[4];
    const float* w2  = (const float*)d_in[5];
    const float* b2  = (const float*)d_in[6];
    const float* eps = (const float*)d_in[7];
    float* out = (float*)d_out;

    char* ws = (char*)d_ws;
    unsigned int*       a3n     = (unsigned int*)(ws);                  // 8 MB nibble a3
    unsigned int*       side    = (unsigned int*)(ws + 8388608);        // 3 MB side-list
    unsigned int*       scnt    = (unsigned int*)(ws + 11534336);       // 16 KB
    int*                nbr     = (int*)(ws + 25165824);                // 1 MB
    int*                deg     = (int*)(ws + 26214400);                // 16 KB
    float*              feats   = (float*)(ws + 26247168);              // 256 KB
    float*              x0      = (float*)(ws + 26509312);              // 1 MB
    float*              x1      = (float*)(ws + 27557888);              // 1 MB
    unsigned long long* abits   = (unsigned long long*)(ws + 28868608); // 2 MB

    hipMemsetAsync(out, 0, 64 * sizeof(float), stream);
    scan_k<<<1024, 256, 0, stream>>>(adj, nbr, deg, abits, feats);
    cra2_k<<<5120, 256, 0, stream>>>(abits, nbr, deg, a3n, side, scnt, feats);
    a4row_k<<<4096, 512, 0, stream>>>(a3n, side, scnt, deg, nbr, feats, e_w, e_b, x0);

    void* args[] = {(void*)&x0, (void*)&x1, (void*)&w1, (void*)&b1,
                    (void*)&w2, (void*)&b2, (void*)&eps, (void*)&nbr,
                    (void*)&deg, (void*)&out};
    hipLaunchCooperativeKernel((const void*)layers_k, dim3(1024), dim3(256),
                               args, 0, stream);
}

// Round 14
// 246.989 us; speedup vs baseline: 1.9991x; 1.9991x over previous
//
#include <hip/hip_runtime.h>
#include <hip/hip_bf16.h>
#include <stdint.h>

#define NN 4096

// Round-34: REVERT to round-31 config (proven 249.2 us best) — grid-sync
// fusion is dead (R12 hand-rolled: 255 us of stale-L1 spin; R13 cooperative
// grid.sync(): 271 us — ~130 us per grid barrier on this 8-XCD part; every
// kernel boundary here is a global dependency, so 6 dispatches is minimal).
// One micro-opt kept: a4row's top-8 extraction packs (val<<6)|lane into the
// DPP max so the owner lane rides along — removes ballot+ffsll from all 16
// extraction rounds. Tie-break by lane is multiset-equivalent -> identical
// output.

__device__ __forceinline__ unsigned int wave_umax_bcast(unsigned int v) {
    // full-wave64 max on the VALU via DPP; result broadcast via readlane.
    int x = (int)v;                           // values < 2^22: signed==unsigned
    x = max(x, __builtin_amdgcn_update_dpp(0, x, 0x111, 0xF, 0xF, true)); // row_shr:1
    x = max(x, __builtin_amdgcn_update_dpp(0, x, 0x112, 0xF, 0xF, true)); // row_shr:2
    x = max(x, __builtin_amdgcn_update_dpp(0, x, 0x114, 0xF, 0xF, true)); // row_shr:4
    x = max(x, __builtin_amdgcn_update_dpp(0, x, 0x118, 0xF, 0xF, true)); // row_shr:8
    x = max(x, __builtin_amdgcn_update_dpp(0, x, 0x142, 0xF, 0xF, true)); // row_bcast:15
    x = max(x, __builtin_amdgcn_update_dpp(0, x, 0x143, 0xF, 0xF, true)); // row_bcast:31
    return (unsigned int)__builtin_amdgcn_readlane(x, 63);
}

// ---------------------------------------------------------------------------
// K1: scan_k — one pass over adj per row with float4 loads (16 B/lane).
// Bit layout of abits: word(e) = ((e>>8)<<2)|(e&3), bit(e) = (e>>2)&63.
// ---------------------------------------------------------------------------
__global__ __launch_bounds__(256) void scan_k(const float* __restrict__ adj,
                                              int* __restrict__ nbr,
                                              int* __restrict__ deg,
                                              unsigned long long* __restrict__ abits,
                                              float* __restrict__ feats) {
    __shared__ int nlist[4][64];
    int tid = threadIdx.x;
    int wv = tid >> 6, ln = tid & 63;
    int v = blockIdx.x * 4 + wv;
    size_t rb = (size_t)v * NN;
    int total = 0;
    unsigned long long w0 = 0;
    const float4* row4 = (const float4*)(adj + rb);
    for (int base = 0; base < NN; base += 256) {
        float4 f = row4[(base >> 2) + ln];
        int q4 = (base >> 8) << 2;
        #pragma unroll
        for (int j = 0; j < 4; j++) {
            float vj = (j == 0) ? f.x : (j == 1) ? f.y : (j == 2) ? f.z : f.w;
            unsigned long long m = __ballot(vj > 0.5f);
            if (vj > 0.5f) {
                int pos = total + __popcll(m & ((1ull << ln) - 1ull));
                if (pos < 64) nlist[wv][pos] = base + 4 * ln + j;
            }
            if (ln == q4 + j) w0 = m;
            total += __popcll(m);
        }
    }
    abits[(size_t)v * 64 + ln] = w0;
    int degL = min(total, 64);
    if (ln < degL) nbr[v * 64 + ln] = nlist[wv][ln];
    if (ln == 0) {
        deg[v] = total;
        float degf = (float)total;
        feats[v * 16 + 12] = degf;
        feats[v * 16 + 13] = degf * degf;
        feats[v * 16 + 14] = degf;           // diag(A^2) = deg (symmetric 0/1)
    }
}

// ---------------------------------------------------------------------------
// K2: cra2_k — role-split merged dispatch:
//   blocks [0, 4096):    pair-list -> a3 (LDS, 2-src weight-1 scatter)
//                        -> STRIDED nibble row + overflow side-list
//   blocks [4096, 5120): cr_feat from the L2-resident bitmask (4 nodes/block)
// ---------------------------------------------------------------------------
__global__ __launch_bounds__(256) void cra2_k(const unsigned long long* __restrict__ abits,
                                              const int* __restrict__ nbr,
                                              const int* __restrict__ deg,
                                              unsigned int* __restrict__ a3n,
                                              unsigned int* __restrict__ side,
                                              unsigned int* __restrict__ scnt,
                                              float* __restrict__ feats) {
    __shared__ __align__(64) unsigned int smem[NN + 196 + 640];
    int tid = threadIdx.x;
    int bid = blockIdx.x;
    int wv = tid >> 6, ln = tid & 63;

    if (bid < NN) {
        // ------------------- a3 role (pair-expanded) -------------------
        unsigned int* acc   = smem;                     // [4096]
        int* us             = (int*)(smem + NN);        // [64]
        int* dus            = (int*)(smem + NN + 64);   // [64]
        unsigned int* pbase = smem + NN + 128;          // [64] excl prefix of dus
        unsigned int* wsumS = smem + NN + 192;          // [4]
        unsigned int* plist = smem + NN + 196;          // [640] (dgw<<12)|w
        int v = bid;
        uint4 z = {0u, 0u, 0u, 0u};
        #pragma unroll
        for (int i = 0; i < 4; i++) ((uint4*)acc)[tid + 256 * i] = z;
        int dv = min(deg[v], 64);
        if (tid < 64) {
            int u = (tid < dv) ? nbr[v * 64 + tid] : 0;
            us[tid] = u;
            int du = (tid < dv) ? min(deg[u], 64) : 0;
            dus[tid] = du;
            // exclusive prefix of dus across wave 0
            int incl = du;
            #pragma unroll
            for (int off = 1; off < 64; off <<= 1) {
                int n = __shfl_up(incl, off, 64);
                if (tid >= off) incl += n;
            }
            pbase[tid] = (unsigned int)(incl - du);
            if (tid == 63) wsumS[0] = (unsigned int)incl;   // total pair count
        }
        __syncthreads();
        int npair = (int)min(wsumS[0], 640u);
        // fill pair list: entry = w | (min(deg[w],64)<<12); direct writes
        for (int p = tid; p < dv * 64; p += 256) {
            int i = p >> 6, j = p & 63;
            if (j < dus[i]) {
                unsigned int pos = pbase[i] + (unsigned int)j;
                if (pos < 640u) {
                    unsigned int w = (unsigned int)nbr[us[i] * 64 + j];
                    plist[pos] = w | ((unsigned int)min(deg[w], 64) << 12);
                }
            }
        }
        __syncthreads();
        // a3 scatter: acc[x] = sum over pairs (u,w) of A[w,x]; weight == 1.
        int lim64 = ((npair + 1) >> 1) << 6;
        for (int q = tid; q < lim64; q += 256) {
            int s = ((q >> 6) << 1) | ((q >> 5) & 1);
            int j = q & 31;
            if (s < npair) {
                unsigned int e = plist[s];
                int dgw = (int)(e >> 12);
                const int* nrw = nbr + (e & 0xFFFu) * 64;
                if (j < dgw) atomicAdd(&acc[nrw[j]], 1u);
                if (j == 31) {
                    for (int jj = 32; jj < dgw; jj++) atomicAdd(&acc[nrw[jj]], 1u);
                }
            }
        }
        __syncthreads();
        // STRIDED nibble emit (word w = cols {w+512k}) + overflow side-list.
        unsigned int wA = 0, wB = 0, ovm = 0;
        #pragma unroll
        for (int k = 0; k < 8; k++) {
            unsigned int a = acc[tid + 512 * k];
            wA |= min(a, 15u) << (4 * k);
            ovm |= (a > 15u ? 1u : 0u) << k;
        }
        #pragma unroll
        for (int k = 0; k < 8; k++) {
            unsigned int a = acc[tid + 256 + 512 * k];
            wB |= min(a, 15u) << (4 * k);
            ovm |= (a > 15u ? 1u : 0u) << (8 + k);
        }
        a3n[(size_t)v * 512 + tid] = wA;
        a3n[(size_t)v * 512 + tid + 256] = wB;
        int lov = __popc(ovm);
        int inc2 = lov;
        #pragma unroll
        for (int off = 1; off < 64; off <<= 1) {
            int n = __shfl_up(inc2, off, 64);
            if (ln >= off) inc2 += n;
        }
        if (ln == 63) wsumS[wv] = (unsigned int)inc2;
        __syncthreads();
        unsigned int wpre2 = 0, totS = 0;
        #pragma unroll
        for (int q = 0; q < 4; q++) {
            unsigned int s = wsumS[q];
            if (q < wv) wpre2 += s;
            totS += s;
        }
        unsigned int pos2 = wpre2 + (unsigned int)(inc2 - lov);
        unsigned int* sideR = side + (size_t)v * 192;
        while (ovm) {
            int i2 = __ffs(ovm) - 1;
            ovm &= ovm - 1;
            unsigned int col = (i2 < 8) ? (unsigned int)(tid + 512 * i2)
                                        : (unsigned int)(tid + 256 + 512 * (i2 - 8));
            unsigned int a = acc[col];
            if (pos2 < 192u) sideR[pos2] = ((a - 15u) << 16) | col;
            pos2++;
        }
        if (tid == 0) scnt[v] = min(totS, 192u);
    } else {
        // ------------------- cr role -------------------
        unsigned long long* rows = (unsigned long long*)smem;   // [4][64], 2 KB
        int* mems = (int*)(smem + 1024);                        // [4][64], 1 KB
        int v = (bid - NN) * 4 + wv;

        int dv = deg[v];
        int degL = min(dv, 64);
        int c = min(dv + 1, 64);

        int nl = (ln < degL) ? nbr[v * 64 + ln] : 0;
        int isless = (ln < degL && nl < v) ? 1 : 0;
        int pos = isless;
        #pragma unroll
        for (int off = 32; off; off >>= 1) pos += __shfl_xor(pos, off, 64);

        int mem = 0;
        if (ln < c) {
            if (ln < pos)       mem = nl;
            else if (ln == pos) mem = v;
            else                mem = nbr[v * 64 + ln - 1];
        }
        mems[wv * 64 + ln] = mem;
        __syncthreads();

        unsigned long long mask = 0ull;
        {
            const unsigned long long* rowb = abits + (size_t)mem * 64;
            for (int j = 0; j < c; j++) {
                int mj = mems[wv * 64 + j];
                unsigned long long w = rowb[((mj >> 8) << 2) | (mj & 3)];
                mask |= ((w >> ((mj >> 2) & 63)) & 1ull) << j;
            }
        }
        if (ln >= c) mask = 0ull;
        rows[wv * 64 + ln] = mask;
        __syncthreads();

        int tpart = 0;
        float epart = 0.f, wpart = 0.f;
        if (ln < c) {
            unsigned long long mm = mask;
            while (mm) {
                int j = __ffsll(mm) - 1;
                mm &= mm - 1;
                tpart += __popcll(mask & rows[wv * 64 + j]);
            }
            if (ln != pos) {
                int cn = __popcll(rows[wv * 64 + pos] & mask);
                float D2 = (float)cn + 1.0f;
                epart = D2;
                wpart = D2 * (D2 - 1.0f) * 0.5f;
            }
        }
        float es = epart, wsum2 = wpart;
        int ts = tpart;
        #pragma unroll
        for (int off = 32; off; off >>= 1) {
            es += __shfl_xor(es, off, 64);
            wsum2 += __shfl_xor(wsum2, off, 64);
            ts += __shfl_xor(ts, off, 64);
        }

        if (ln == 0) {
            float degf = (float)dv;
            float k = degf + 1.0f;
            float E = 0.5f * (es + degf);
            float W = wsum2 + degf * (degf - 1.0f) * 0.5f;
            float T = (float)ts / 6.0f;
            float f3 = T;
            float f2 = W - 3.0f * T;
            float f1 = E * (k - 2.0f) - 2.0f * f2 - 3.0f * f3;
            float tot2 = k * (k - 1.0f) * (k - 2.0f) / 6.0f;
            float f0 = tot2 - f1 - f2 - f3;
            if (k < 3.0f) { f0 = f1 = f2 = f3 = 0.f; }
            float s = f0 + f1 + f2 + f3 + 1e-10f;
            feats[v * 16 + 0] = f0 / s;
            feats[v * 16 + 1] = f1 / s;
            feats[v * 16 + 2] = f2 / s;
            feats[v * 16 + 3] = f3 / s;
        }
    }
}

// ---------------------------------------------------------------------------
// K4: fused a4-row (register-gather over strided nibble a3 + side-list) +
// top-8 + embedding. Max-reduces on VALU DPP with (val<<6)|lane keys.
// ---------------------------------------------------------------------------
__global__ __launch_bounds__(512) void a4row_k(const unsigned int* __restrict__ a3n,
                                               const unsigned int* __restrict__ side,
                                               const unsigned int* __restrict__ scnt,
                                               const int* __restrict__ deg,
                                               const int* __restrict__ nbr,
                                               const float* __restrict__ feats,
                                               const float* __restrict__ e_w,
                                               const float* __restrict__ e_b,
                                               float* __restrict__ x0) {
    __shared__ unsigned int sacc[NN];        // 16 KB u32 side accumulator
    __shared__ unsigned int sbase[64];       // u*512 (word base of a3 row)
    __shared__ unsigned int sbs[64];         // u*192 (side base)
    __shared__ unsigned int sS[64];          // side counts
    __shared__ unsigned int wtops[64];
    int tid = threadIdx.x;
    int wv = tid >> 6, ln = tid & 63;
    int v = blockIdx.x;

    {
        uint4 z = {0u, 0u, 0u, 0u};
        ((uint4*)sacc)[tid] = z;
        ((uint4*)sacc)[tid + 512] = z;
    }
    int dvv = min(deg[v], 64);
    if (tid < dvv) {
        unsigned int u = (unsigned int)nbr[v * 64 + tid];
        sbase[tid] = u * 512u;
        sbs[tid]   = u * 192u;
        sS[tid]    = scnt[u];
    }
    __syncthreads();

    // side scatter (few hundred entries; hides under the base loop)
    for (int i = wv; i < dvv; i += 8) {
        int ns = (int)sS[i];
        const unsigned int* sp = side + sbs[i];
        for (int g2 = ln; g2 < ns; g2 += 64) {
            unsigned int e = sp[g2];
            atomicAdd(&sacc[e & 0xFFFu], e >> 16);
        }
    }

    // base: register gather-accumulate (owner-columns, strided layout)
    unsigned int aE = 0, aO = 0;
    unsigned int SE0 = 0, SE1 = 0, SO0 = 0, SO1 = 0;
    for (int s0 = 0; s0 < dvv; s0 += 16) {
        int se = min(s0 + 16, dvv);
        for (int s = s0; s < se; s++) {
            unsigned int w = a3n[sbase[s] + (unsigned int)tid];
            aE += w & 0x0F0F0F0Fu;
            aO += (w >> 4) & 0x0F0F0F0Fu;
        }
        SE0 += __builtin_amdgcn_perm(0u, aE, 0x0c010c00u);   // {aE.b0, aE.b1} u16
        SE1 += __builtin_amdgcn_perm(0u, aE, 0x0c030c02u);   // {aE.b2, aE.b3}
        SO0 += __builtin_amdgcn_perm(0u, aO, 0x0c010c00u);
        SO1 += __builtin_amdgcn_perm(0u, aO, 0x0c030c02u);
        aE = 0; aO = 0;
    }
    __syncthreads();

    // merge side sums with register base sums (strided col map).
    unsigned int vv[8];
    vv[0] = (SE0 & 0xFFFFu) + sacc[tid];
    vv[1] = (SO0 & 0xFFFFu) + sacc[tid + 512];
    vv[2] = (SE0 >> 16)     + sacc[tid + 1024];
    vv[3] = (SO0 >> 16)     + sacc[tid + 1536];
    vv[4] = (SE1 & 0xFFFFu) + sacc[tid + 2048];
    vv[5] = (SO1 & 0xFFFFu) + sacc[tid + 2560];
    vv[6] = (SE1 >> 16)     + sacc[tid + 3072];
    vv[7] = (SO1 >> 16)     + sacc[tid + 3584];

    // per-thread top-8 over the 8 owned columns
    unsigned int best[8];
    #pragma unroll
    for (int q = 0; q < 8; q++) best[q] = 0u;
    #pragma unroll
    for (int m = 0; m < 8; m++) {
        unsigned int val = vv[m];
        if (val > best[7]) {
            best[7] = val;
            #pragma unroll
            for (int s = 7; s > 0; s--) {
                if (best[s] > best[s - 1]) {
                    unsigned int t2 = best[s - 1]; best[s - 1] = best[s]; best[s] = t2;
                } else break;
            }
        }
    }

    // per-wave extract of 8 maxima (DPP max-reduce on (val<<6)|lane keys:
    // owner lane rides in the low bits — no ballot/ffs needed)
    unsigned int wave_val = 0u;
    #pragma unroll
    for (int r = 0; r < 8; r++) {
        unsigned int kmax = wave_umax_bcast((best[0] << 6) | (unsigned int)ln);
        if (ln == (int)(kmax & 63u)) {
            #pragma unroll
            for (int s = 0; s < 7; s++) best[s] = best[s + 1];
            best[7] = 0u;
        }
        if (ln == r) wave_val = kmax >> 6;
    }
    if (ln < 8) wtops[wv * 8 + ln] = wave_val;
    __syncthreads();

    // wave 0: merge 64 candidates, then fused embedding
    if (wv == 0) {
        unsigned int cand = wtops[ln];
        unsigned int myv = 0u;
        #pragma unroll
        for (int r = 0; r < 8; r++) {
            unsigned int kmax = wave_umax_bcast((cand << 6) | (unsigned int)ln);
            if (ln == (int)(kmax & 63u)) cand = 0u;
            if (ln == r) myv = kmax >> 6;
        }
        int d = ln;
        float s = e_b[d];
        s += feats[v * 16 + 0]  * e_w[0 * 64 + d];
        s += feats[v * 16 + 1]  * e_w[1 * 64 + d];
        s += feats[v * 16 + 2]  * e_w[2 * 64 + d];
        s += feats[v * 16 + 3]  * e_w[3 * 64 + d];
        #pragma unroll
        for (int j = 0; j < 8; j++) {
            float mj = (float)(unsigned int)__shfl((int)myv, j, 64);
            s += mj * e_w[(4 + j) * 64 + d];
        }
        s += feats[v * 16 + 12] * e_w[12 * 64 + d];
        s += feats[v * 16 + 13] * e_w[13 * 64 + d];
        s += feats[v * 16 + 14] * e_w[14 * 64 + d];
        x0[(size_t)v * 64 + d] = s;
    }
}

// ---------------------------------------------------------------------------
// K5: one GNN layer, weights LDS-staged. For li==2, accumulate block column
// sums directly into out[64] via fp32 atomics.
// ---------------------------------------------------------------------------
__global__ __launch_bounds__(256) void layer_k(const float* __restrict__ xin,
                                               float* __restrict__ xout,
                                               const float* __restrict__ w1,
                                               const float* __restrict__ b1,
                                               const float* __restrict__ w2,
                                               const float* __restrict__ b2,
                                               const float* __restrict__ eps,
                                               const int* __restrict__ nbr,
                                               const int* __restrict__ deg,
                                               float* __restrict__ out,
                                               int li) {
    __shared__ float wL[4096];                // 16 KB, reused for w1 then w2
    __shared__ float h[4][64], t[4][64];
    int tid = threadIdx.x;
    int wv = tid >> 6, d = tid & 63;
    int v = blockIdx.x * 4 + wv;

    // stage w1 (coalesced float4)
    {
        const float4* src = (const float4*)(w1 + li * 4096);
        #pragma unroll
        for (int i = 0; i < 4; i++) ((float4*)wL)[tid + 256 * i] = src[tid + 256 * i];
    }

    float xv = xin[(size_t)v * 64 + d];
    int dv = min(deg[v], 64);
    const int* nl = nbr + v * 64;
    float agg = 0.f;
    int j = 0;
    for (; j + 4 <= dv; j += 4) {
        int n0 = nl[j], n1 = nl[j + 1], n2 = nl[j + 2], n3 = nl[j + 3];
        float a0 = xin[(size_t)n0 * 64 + d];
        float a1 = xin[(size_t)n1 * 64 + d];
        float a2v = xin[(size_t)n2 * 64 + d];
        float a3 = xin[(size_t)n3 * 64 + d];
        agg += (a0 + a1) + (a2v + a3);
    }
    for (; j < dv; j++) agg += xin[(size_t)nl[j] * 64 + d];
    float hv = (1.0f + eps[li]) * xv + agg;
    h[wv][d] = hv;
    __syncthreads();

    float s = b1[li * 64 + d];
    #pragma unroll 8
    for (int k = 0; k < 64; k++) s += h[wv][k] * wL[k * 64 + d];
    s = fmaxf(s, 0.f);
    t[wv][d] = s;
    __syncthreads();

    // stage w2 (reuse wL)
    {
        const float4* src = (const float4*)(w2 + li * 4096);
        #pragma unroll
        for (int i = 0; i < 4; i++) ((float4*)wL)[tid + 256 * i] = src[tid + 256 * i];
    }
    __syncthreads();

    float o = b2[li * 64 + d];
    #pragma unroll 8
    for (int k = 0; k < 64; k++) o += t[wv][k] * wL[k * 64 + d];
    if (li == 2) {
        h[wv][d] = o;
        __syncthreads();
        if (wv == 0)
            atomicAdd(&out[d], (h[0][d] + h[1][d]) + (h[2][d] + h[3][d]));
    } else {
        xout[(size_t)v * 64 + d] = o;
    }
}

// ---------------------------------------------------------------------------
extern "C" void kernel_launch(void* const* d_in, const int* in_sizes, int n_in,
                              void* d_out, int out_size, void* d_ws, size_t ws_size,
                              hipStream_t stream) {
    const float* adj = (const float*)d_in[0];
    const float* e_w = (const float*)d_in[1];
    const float* e_b = (const float*)d_in[2];
    const float* w1  = (const float*)d_in[3];
    const float* b1  = (const float*)d_in[4];
    const float* w2  = (const float*)d_in[5];
    const float* b2  = (const float*)d_in[6];
    const float* eps = (const float*)d_in[7];
    float* out = (float*)d_out;

    char* ws = (char*)d_ws;
    unsigned int*       a3n     = (unsigned int*)(ws);                  // 8 MB nibble a3
    unsigned int*       side    = (unsigned int*)(ws + 8388608);        // 3 MB side-list
    unsigned int*       scnt    = (unsigned int*)(ws + 11534336);       // 16 KB
    int*                nbr     = (int*)(ws + 25165824);                // 1 MB
    int*                deg     = (int*)(ws + 26214400);                // 16 KB
    float*              feats   = (float*)(ws + 26247168);              // 256 KB
    float*              x0      = (float*)(ws + 26509312);              // 1 MB
    float*              x1      = (float*)(ws + 27557888);              // 1 MB
    unsigned long long* abits   = (unsigned long long*)(ws + 28868608); // 2 MB

    hipMemsetAsync(out, 0, 64 * sizeof(float), stream);
    scan_k<<<1024, 256, 0, stream>>>(adj, nbr, deg, abits, feats);
    cra2_k<<<5120, 256, 0, stream>>>(abits, nbr, deg, a3n, side, scnt, feats);
    a4row_k<<<4096, 512, 0, stream>>>(a3n, side, scnt, deg, nbr, feats, e_w, e_b, x0);
    layer_k<<<1024, 256, 0, stream>>>(x0, x1, w1, b1, w2, b2, eps, nbr, deg, out, 0);
    layer_k<<<1024, 256, 0, stream>>>(x1, x0, w1, b1, w2, b2, eps, nbr, deg, out, 1);
    layer_k<<<1024, 256, 0, stream>>>(x0, x1, w1, b1, w2, b2, eps, nbr, deg, out, 2);
}

// Round 15
// 241.439 us; speedup vs baseline: 2.0450x; 1.0230x over previous
//
#include <hip/hip_runtime.h>
#include <hip/hip_bf16.h>
#include <stdint.h>

#define NN 4096

// Round-35: a4row goes 512 -> 256 threads, 2 owned words (16 cols) per
// thread via uint2 loads. The per-wave DPP top-8 extraction (~136 VALU) is
// a fixed per-wave cost: extraction rounds per block drop 72 -> 40 while
// per-column work (accumulate/insert) is thread-count invariant. Occupancy
// unchanged (8 blocks/CU x 4 waves = 32 waves/CU). Everything else is the
// proven R14 config (pair-expanded cra2, strided nibble a3, DPP extraction
// with (val<<6)|lane keys, LDS-staged layer_k, 6 dispatches).

__device__ __forceinline__ unsigned int wave_umax_bcast(unsigned int v) {
    // full-wave64 max on the VALU via DPP; result broadcast via readlane.
    int x = (int)v;                           // values < 2^22: signed==unsigned
    x = max(x, __builtin_amdgcn_update_dpp(0, x, 0x111, 0xF, 0xF, true)); // row_shr:1
    x = max(x, __builtin_amdgcn_update_dpp(0, x, 0x112, 0xF, 0xF, true)); // row_shr:2
    x = max(x, __builtin_amdgcn_update_dpp(0, x, 0x114, 0xF, 0xF, true)); // row_shr:4
    x = max(x, __builtin_amdgcn_update_dpp(0, x, 0x118, 0xF, 0xF, true)); // row_shr:8
    x = max(x, __builtin_amdgcn_update_dpp(0, x, 0x142, 0xF, 0xF, true)); // row_bcast:15
    x = max(x, __builtin_amdgcn_update_dpp(0, x, 0x143, 0xF, 0xF, true)); // row_bcast:31
    return (unsigned int)__builtin_amdgcn_readlane(x, 63);
}

// ---------------------------------------------------------------------------
// K1: scan_k — one pass over adj per row with float4 loads (16 B/lane).
// Bit layout of abits: word(e) = ((e>>8)<<2)|(e&3), bit(e) = (e>>2)&63.
// ---------------------------------------------------------------------------
__global__ __launch_bounds__(256) void scan_k(const float* __restrict__ adj,
                                              int* __restrict__ nbr,
                                              int* __restrict__ deg,
                                              unsigned long long* __restrict__ abits,
                                              float* __restrict__ feats) {
    __shared__ int nlist[4][64];
    int tid = threadIdx.x;
    int wv = tid >> 6, ln = tid & 63;
    int v = blockIdx.x * 4 + wv;
    size_t rb = (size_t)v * NN;
    int total = 0;
    unsigned long long w0 = 0;
    const float4* row4 = (const float4*)(adj + rb);
    for (int base = 0; base < NN; base += 256) {
        float4 f = row4[(base >> 2) + ln];
        int q4 = (base >> 8) << 2;
        #pragma unroll
        for (int j = 0; j < 4; j++) {
            float vj = (j == 0) ? f.x : (j == 1) ? f.y : (j == 2) ? f.z : f.w;
            unsigned long long m = __ballot(vj > 0.5f);
            if (vj > 0.5f) {
                int pos = total + __popcll(m & ((1ull << ln) - 1ull));
                if (pos < 64) nlist[wv][pos] = base + 4 * ln + j;
            }
            if (ln == q4 + j) w0 = m;
            total += __popcll(m);
        }
    }
    abits[(size_t)v * 64 + ln] = w0;
    int degL = min(total, 64);
    if (ln < degL) nbr[v * 64 + ln] = nlist[wv][ln];
    if (ln == 0) {
        deg[v] = total;
        float degf = (float)total;
        feats[v * 16 + 12] = degf;
        feats[v * 16 + 13] = degf * degf;
        feats[v * 16 + 14] = degf;           // diag(A^2) = deg (symmetric 0/1)
    }
}

// ---------------------------------------------------------------------------
// K2: cra2_k — role-split merged dispatch:
//   blocks [0, 4096):    pair-list -> a3 (LDS, 2-src weight-1 scatter)
//                        -> STRIDED nibble row + overflow side-list
//   blocks [4096, 5120): cr_feat from the L2-resident bitmask (4 nodes/block)
// ---------------------------------------------------------------------------
__global__ __launch_bounds__(256) void cra2_k(const unsigned long long* __restrict__ abits,
                                              const int* __restrict__ nbr,
                                              const int* __restrict__ deg,
                                              unsigned int* __restrict__ a3n,
                                              unsigned int* __restrict__ side,
                                              unsigned int* __restrict__ scnt,
                                              float* __restrict__ feats) {
    __shared__ __align__(64) unsigned int smem[NN + 196 + 640];
    int tid = threadIdx.x;
    int bid = blockIdx.x;
    int wv = tid >> 6, ln = tid & 63;

    if (bid < NN) {
        // ------------------- a3 role (pair-expanded) -------------------
        unsigned int* acc   = smem;                     // [4096]
        int* us             = (int*)(smem + NN);        // [64]
        int* dus            = (int*)(smem + NN + 64);   // [64]
        unsigned int* pbase = smem + NN + 128;          // [64] excl prefix of dus
        unsigned int* wsumS = smem + NN + 192;          // [4]
        unsigned int* plist = smem + NN + 196;          // [640] (dgw<<12)|w
        int v = bid;
        uint4 z = {0u, 0u, 0u, 0u};
        #pragma unroll
        for (int i = 0; i < 4; i++) ((uint4*)acc)[tid + 256 * i] = z;
        int dv = min(deg[v], 64);
        if (tid < 64) {
            int u = (tid < dv) ? nbr[v * 64 + tid] : 0;
            us[tid] = u;
            int du = (tid < dv) ? min(deg[u], 64) : 0;
            dus[tid] = du;
            // exclusive prefix of dus across wave 0
            int incl = du;
            #pragma unroll
            for (int off = 1; off < 64; off <<= 1) {
                int n = __shfl_up(incl, off, 64);
                if (tid >= off) incl += n;
            }
            pbase[tid] = (unsigned int)(incl - du);
            if (tid == 63) wsumS[0] = (unsigned int)incl;   // total pair count
        }
        __syncthreads();
        int npair = (int)min(wsumS[0], 640u);
        // fill pair list: entry = w | (min(deg[w],64)<<12); direct writes
        for (int p = tid; p < dv * 64; p += 256) {
            int i = p >> 6, j = p & 63;
            if (j < dus[i]) {
                unsigned int pos = pbase[i] + (unsigned int)j;
                if (pos < 640u) {
                    unsigned int w = (unsigned int)nbr[us[i] * 64 + j];
                    plist[pos] = w | ((unsigned int)min(deg[w], 64) << 12);
                }
            }
        }
        __syncthreads();
        // a3 scatter: acc[x] = sum over pairs (u,w) of A[w,x]; weight == 1.
        int lim64 = ((npair + 1) >> 1) << 6;
        for (int q = tid; q < lim64; q += 256) {
            int s = ((q >> 6) << 1) | ((q >> 5) & 1);
            int j = q & 31;
            if (s < npair) {
                unsigned int e = plist[s];
                int dgw = (int)(e >> 12);
                const int* nrw = nbr + (e & 0xFFFu) * 64;
                if (j < dgw) atomicAdd(&acc[nrw[j]], 1u);
                if (j == 31) {
                    for (int jj = 32; jj < dgw; jj++) atomicAdd(&acc[nrw[jj]], 1u);
                }
            }
        }
        __syncthreads();
        // STRIDED nibble emit (word w = cols {w+512k}) + overflow side-list.
        unsigned int wA = 0, wB = 0, ovm = 0;
        #pragma unroll
        for (int k = 0; k < 8; k++) {
            unsigned int a = acc[tid + 512 * k];
            wA |= min(a, 15u) << (4 * k);
            ovm |= (a > 15u ? 1u : 0u) << k;
        }
        #pragma unroll
        for (int k = 0; k < 8; k++) {
            unsigned int a = acc[tid + 256 + 512 * k];
            wB |= min(a, 15u) << (4 * k);
            ovm |= (a > 15u ? 1u : 0u) << (8 + k);
        }
        a3n[(size_t)v * 512 + tid] = wA;
        a3n[(size_t)v * 512 + tid + 256] = wB;
        int lov = __popc(ovm);
        int inc2 = lov;
        #pragma unroll
        for (int off = 1; off < 64; off <<= 1) {
            int n = __shfl_up(inc2, off, 64);
            if (ln >= off) inc2 += n;
        }
        if (ln == 63) wsumS[wv] = (unsigned int)inc2;
        __syncthreads();
        unsigned int wpre2 = 0, totS = 0;
        #pragma unroll
        for (int q = 0; q < 4; q++) {
            unsigned int s = wsumS[q];
            if (q < wv) wpre2 += s;
            totS += s;
        }
        unsigned int pos2 = wpre2 + (unsigned int)(inc2 - lov);
        unsigned int* sideR = side + (size_t)v * 192;
        while (ovm) {
            int i2 = __ffs(ovm) - 1;
            ovm &= ovm - 1;
            unsigned int col = (i2 < 8) ? (unsigned int)(tid + 512 * i2)
                                        : (unsigned int)(tid + 256 + 512 * (i2 - 8));
            unsigned int a = acc[col];
            if (pos2 < 192u) sideR[pos2] = ((a - 15u) << 16) | col;
            pos2++;
        }
        if (tid == 0) scnt[v] = min(totS, 192u);
    } else {
        // ------------------- cr role -------------------
        unsigned long long* rows = (unsigned long long*)smem;   // [4][64], 2 KB
        int* mems = (int*)(smem + 1024);                        // [4][64], 1 KB
        int v = (bid - NN) * 4 + wv;

        int dv = deg[v];
        int degL = min(dv, 64);
        int c = min(dv + 1, 64);

        int nl = (ln < degL) ? nbr[v * 64 + ln] : 0;
        int isless = (ln < degL && nl < v) ? 1 : 0;
        int pos = isless;
        #pragma unroll
        for (int off = 32; off; off >>= 1) pos += __shfl_xor(pos, off, 64);

        int mem = 0;
        if (ln < c) {
            if (ln < pos)       mem = nl;
            else if (ln == pos) mem = v;
            else                mem = nbr[v * 64 + ln - 1];
        }
        mems[wv * 64 + ln] = mem;
        __syncthreads();

        unsigned long long mask = 0ull;
        {
            const unsigned long long* rowb = abits + (size_t)mem * 64;
            for (int j = 0; j < c; j++) {
                int mj = mems[wv * 64 + j];
                unsigned long long w = rowb[((mj >> 8) << 2) | (mj & 3)];
                mask |= ((w >> ((mj >> 2) & 63)) & 1ull) << j;
            }
        }
        if (ln >= c) mask = 0ull;
        rows[wv * 64 + ln] = mask;
        __syncthreads();

        int tpart = 0;
        float epart = 0.f, wpart = 0.f;
        if (ln < c) {
            unsigned long long mm = mask;
            while (mm) {
                int j = __ffsll(mm) - 1;
                mm &= mm - 1;
                tpart += __popcll(mask & rows[wv * 64 + j]);
            }
            if (ln != pos) {
                int cn = __popcll(rows[wv * 64 + pos] & mask);
                float D2 = (float)cn + 1.0f;
                epart = D2;
                wpart = D2 * (D2 - 1.0f) * 0.5f;
            }
        }
        float es = epart, wsum2 = wpart;
        int ts = tpart;
        #pragma unroll
        for (int off = 32; off; off >>= 1) {
            es += __shfl_xor(es, off, 64);
            wsum2 += __shfl_xor(wsum2, off, 64);
            ts += __shfl_xor(ts, off, 64);
        }

        if (ln == 0) {
            float degf = (float)dv;
            float k = degf + 1.0f;
            float E = 0.5f * (es + degf);
            float W = wsum2 + degf * (degf - 1.0f) * 0.5f;
            float T = (float)ts / 6.0f;
            float f3 = T;
            float f2 = W - 3.0f * T;
            float f1 = E * (k - 2.0f) - 2.0f * f2 - 3.0f * f3;
            float tot2 = k * (k - 1.0f) * (k - 2.0f) / 6.0f;
            float f0 = tot2 - f1 - f2 - f3;
            if (k < 3.0f) { f0 = f1 = f2 = f3 = 0.f; }
            float s = f0 + f1 + f2 + f3 + 1e-10f;
            feats[v * 16 + 0] = f0 / s;
            feats[v * 16 + 1] = f1 / s;
            feats[v * 16 + 2] = f2 / s;
            feats[v * 16 + 3] = f3 / s;
        }
    }
}

// ---------------------------------------------------------------------------
// K4: fused a4-row (register-gather over strided nibble a3 + side-list) +
// top-8 + embedding. 256 threads, 2 owned words (16 cols) per thread via
// uint2 loads; DPP max-reduce extraction with (val<<6)|lane keys.
// Word w covers cols {w+512k}; thread owns words {2tid, 2tid+1}.
// ---------------------------------------------------------------------------
__global__ __launch_bounds__(256) void a4row_k(const unsigned int* __restrict__ a3n,
                                               const unsigned int* __restrict__ side,
                                               const unsigned int* __restrict__ scnt,
                                               const int* __restrict__ deg,
                                               const int* __restrict__ nbr,
                                               const float* __restrict__ feats,
                                               const float* __restrict__ e_w,
                                               const float* __restrict__ e_b,
                                               float* __restrict__ x0) {
    __shared__ unsigned int sacc[NN];        // 16 KB u32 side accumulator
    __shared__ unsigned int sbase[64];       // u*512 (word base of a3 row)
    __shared__ unsigned int sbs[64];         // u*192 (side base)
    __shared__ unsigned int sS[64];          // side counts
    __shared__ unsigned int wtops[32];
    int tid = threadIdx.x;
    int wv = tid >> 6, ln = tid & 63;
    int v = blockIdx.x;

    {
        uint4 z = {0u, 0u, 0u, 0u};
        #pragma unroll
        for (int i = 0; i < 4; i++) ((uint4*)sacc)[tid + 256 * i] = z;
    }
    int dvv = min(deg[v], 64);
    if (tid < dvv) {
        unsigned int u = (unsigned int)nbr[v * 64 + tid];
        sbase[tid] = u * 512u;
        sbs[tid]   = u * 192u;
        sS[tid]    = scnt[u];
    }
    __syncthreads();

    // side scatter (few hundred entries; hides under the base loop)
    for (int i = wv; i < dvv; i += 4) {
        int ns = (int)sS[i];
        const unsigned int* sp = side + sbs[i];
        for (int g2 = ln; g2 < ns; g2 += 64) {
            unsigned int e = sp[g2];
            atomicAdd(&sacc[e & 0xFFFu], e >> 16);
        }
    }

    // base: register gather-accumulate, 2 words per thread (uint2 loads)
    unsigned int aE0 = 0, aO0 = 0, aE1 = 0, aO1 = 0;
    unsigned int SE00 = 0, SE01 = 0, SO00 = 0, SO01 = 0;
    unsigned int SE10 = 0, SE11 = 0, SO10 = 0, SO11 = 0;
    for (int s0 = 0; s0 < dvv; s0 += 16) {
        int se = min(s0 + 16, dvv);
        for (int s = s0; s < se; s++) {
            uint2 W = ((const uint2*)(a3n + sbase[s]))[tid];
            aE0 += W.x & 0x0F0F0F0Fu;
            aO0 += (W.x >> 4) & 0x0F0F0F0Fu;
            aE1 += W.y & 0x0F0F0F0Fu;
            aO1 += (W.y >> 4) & 0x0F0F0F0Fu;
        }
        SE00 += __builtin_amdgcn_perm(0u, aE0, 0x0c010c00u);  // {b0,b1} as u16
        SE01 += __builtin_amdgcn_perm(0u, aE0, 0x0c030c02u);  // {b2,b3}
        SO00 += __builtin_amdgcn_perm(0u, aO0, 0x0c010c00u);
        SO01 += __builtin_amdgcn_perm(0u, aO0, 0x0c030c02u);
        SE10 += __builtin_amdgcn_perm(0u, aE1, 0x0c010c00u);
        SE11 += __builtin_amdgcn_perm(0u, aE1, 0x0c030c02u);
        SO10 += __builtin_amdgcn_perm(0u, aO1, 0x0c010c00u);
        SO11 += __builtin_amdgcn_perm(0u, aO1, 0x0c030c02u);
        aE0 = 0; aO0 = 0; aE1 = 0; aO1 = 0;
    }
    __syncthreads();

    // merge side sums with register base sums.
    // word w=2tid+h, nibble i = col w+512i. sacc pair reads are uint2:
    // ((uint2*)sacc)[tid+256k] = {sacc[2tid+512k], sacc[2tid+1+512k]}.
    unsigned int vv[16];
    {
        uint2 u0 = ((uint2*)sacc)[tid];
        uint2 u1 = ((uint2*)sacc)[tid + 256];
        uint2 u2 = ((uint2*)sacc)[tid + 512];
        uint2 u3 = ((uint2*)sacc)[tid + 768];
        uint2 u4 = ((uint2*)sacc)[tid + 1024];
        uint2 u5 = ((uint2*)sacc)[tid + 1280];
        uint2 u6 = ((uint2*)sacc)[tid + 1536];
        uint2 u7 = ((uint2*)sacc)[tid + 1792];
        vv[0]  = (SE00 & 0xFFFFu) + u0.x;  vv[8]  = (SE10 & 0xFFFFu) + u0.y;
        vv[1]  = (SO00 & 0xFFFFu) + u1.x;  vv[9]  = (SO10 & 0xFFFFu) + u1.y;
        vv[2]  = (SE00 >> 16)     + u2.x;  vv[10] = (SE10 >> 16)     + u2.y;
        vv[3]  = (SO00 >> 16)     + u3.x;  vv[11] = (SO10 >> 16)     + u3.y;
        vv[4]  = (SE01 & 0xFFFFu) + u4.x;  vv[12] = (SE11 & 0xFFFFu) + u4.y;
        vv[5]  = (SO01 & 0xFFFFu) + u5.x;  vv[13] = (SO11 & 0xFFFFu) + u5.y;
        vv[6]  = (SE01 >> 16)     + u6.x;  vv[14] = (SE11 >> 16)     + u6.y;
        vv[7]  = (SO01 >> 16)     + u7.x;  vv[15] = (SO11 >> 16)     + u7.y;
    }

    // per-thread top-8 over the 16 owned columns
    unsigned int best[8];
    #pragma unroll
    for (int q = 0; q < 8; q++) best[q] = 0u;
    #pragma unroll
    for (int m = 0; m < 16; m++) {
        unsigned int val = vv[m];
        if (val > best[7]) {
            best[7] = val;
            #pragma unroll
            for (int s = 7; s > 0; s--) {
                if (best[s] > best[s - 1]) {
                    unsigned int t2 = best[s - 1]; best[s - 1] = best[s]; best[s] = t2;
                } else break;
            }
        }
    }

    // per-wave extract of 8 maxima (DPP max-reduce on (val<<6)|lane keys)
    unsigned int wave_val = 0u;
    #pragma unroll
    for (int r = 0; r < 8; r++) {
        unsigned int kmax = wave_umax_bcast((best[0] << 6) | (unsigned int)ln);
        if (ln == (int)(kmax & 63u)) {
            #pragma unroll
            for (int s = 0; s < 7; s++) best[s] = best[s + 1];
            best[7] = 0u;
        }
        if (ln == r) wave_val = kmax >> 6;
    }
    if (ln < 8) wtops[wv * 8 + ln] = wave_val;
    __syncthreads();

    // wave 0: merge 32 candidates, then fused embedding
    if (wv == 0) {
        unsigned int cand = (ln < 32) ? wtops[ln] : 0u;
        unsigned int myv = 0u;
        #pragma unroll
        for (int r = 0; r < 8; r++) {
            unsigned int kmax = wave_umax_bcast((cand << 6) | (unsigned int)ln);
            if (ln == (int)(kmax & 63u)) cand = 0u;
            if (ln == r) myv = kmax >> 6;
        }
        int d = ln;
        float s = e_b[d];
        s += feats[v * 16 + 0]  * e_w[0 * 64 + d];
        s += feats[v * 16 + 1]  * e_w[1 * 64 + d];
        s += feats[v * 16 + 2]  * e_w[2 * 64 + d];
        s += feats[v * 16 + 3]  * e_w[3 * 64 + d];
        #pragma unroll
        for (int j = 0; j < 8; j++) {
            float mj = (float)(unsigned int)__shfl((int)myv, j, 64);
            s += mj * e_w[(4 + j) * 64 + d];
        }
        s += feats[v * 16 + 12] * e_w[12 * 64 + d];
        s += feats[v * 16 + 13] * e_w[13 * 64 + d];
        s += feats[v * 16 + 14] * e_w[14 * 64 + d];
        x0[(size_t)v * 64 + d] = s;
    }
}

// ---------------------------------------------------------------------------
// K5: one GNN layer, weights LDS-staged. For li==2, accumulate block column
// sums directly into out[64] via fp32 atomics.
// ---------------------------------------------------------------------------
__global__ __launch_bounds__(256) void layer_k(const float* __restrict__ xin,
                                               float* __restrict__ xout,
                                               const float* __restrict__ w1,
                                               const float* __restrict__ b1,
                                               const float* __restrict__ w2,
                                               const float* __restrict__ b2,
                                               const float* __restrict__ eps,
                                               const int* __restrict__ nbr,
                                               const int* __restrict__ deg,
                                               float* __restrict__ out,
                                               int li) {
    __shared__ float wL[4096];                // 16 KB, reused for w1 then w2
    __shared__ float h[4][64], t[4][64];
    int tid = threadIdx.x;
    int wv = tid >> 6, d = tid & 63;
    int v = blockIdx.x * 4 + wv;

    // stage w1 (coalesced float4)
    {
        const float4* src = (const float4*)(w1 + li * 4096);
        #pragma unroll
        for (int i = 0; i < 4; i++) ((float4*)wL)[tid + 256 * i] = src[tid + 256 * i];
    }

    float xv = xin[(size_t)v * 64 + d];
    int dv = min(deg[v], 64);
    const int* nl = nbr + v * 64;
    float agg = 0.f;
    int j = 0;
    for (; j + 4 <= dv; j += 4) {
        int n0 = nl[j], n1 = nl[j + 1], n2 = nl[j + 2], n3 = nl[j + 3];
        float a0 = xin[(size_t)n0 * 64 + d];
        float a1 = xin[(size_t)n1 * 64 + d];
        float a2v = xin[(size_t)n2 * 64 + d];
        float a3 = xin[(size_t)n3 * 64 + d];
        agg += (a0 + a1) + (a2v + a3);
    }
    for (; j < dv; j++) agg += xin[(size_t)nl[j] * 64 + d];
    float hv = (1.0f + eps[li]) * xv + agg;
    h[wv][d] = hv;
    __syncthreads();

    float s = b1[li * 64 + d];
    #pragma unroll 8
    for (int k = 0; k < 64; k++) s += h[wv][k] * wL[k * 64 + d];
    s = fmaxf(s, 0.f);
    t[wv][d] = s;
    __syncthreads();

    // stage w2 (reuse wL)
    {
        const float4* src = (const float4*)(w2 + li * 4096);
        #pragma unroll
        for (int i = 0; i < 4; i++) ((float4*)wL)[tid + 256 * i] = src[tid + 256 * i];
    }
    __syncthreads();

    float o = b2[li * 64 + d];
    #pragma unroll 8
    for (int k = 0; k < 64; k++) o += t[wv][k] * wL[k * 64 + d];
    if (li == 2) {
        h[wv][d] = o;
        __syncthreads();
        if (wv == 0)
            atomicAdd(&out[d], (h[0][d] + h[1][d]) + (h[2][d] + h[3][d]));
    } else {
        xout[(size_t)v * 64 + d] = o;
    }
}

// ---------------------------------------------------------------------------
extern "C" void kernel_launch(void* const* d_in, const int* in_sizes, int n_in,
                              void* d_out, int out_size, void* d_ws, size_t ws_size,
                              hipStream_t stream) {
    const float* adj = (const float*)d_in[0];
    const float* e_w = (const float*)d_in[1];
    const float* e_b = (const float*)d_in[2];
    const float* w1  = (const float*)d_in[3];
    const float* b1  = (const float*)d_in[4];
    const float* w2  = (const float*)d_in[5];
    const float* b2  = (const float*)d_in[6];
    const float* eps = (const float*)d_in[7];
    float* out = (float*)d_out;

    char* ws = (char*)d_ws;
    unsigned int*       a3n     = (unsigned int*)(ws);                  // 8 MB nibble a3
    unsigned int*       side    = (unsigned int*)(ws + 8388608);        // 3 MB side-list
    unsigned int*       scnt    = (unsigned int*)(ws + 11534336);       // 16 KB
    int*                nbr     = (int*)(ws + 25165824);                // 1 MB
    int*                deg     = (int*)(ws + 26214400);                // 16 KB
    float*              feats   = (float*)(ws + 26247168);              // 256 KB
    float*              x0      = (float*)(ws + 26509312);              // 1 MB
    float*              x1      = (float*)(ws + 27557888);              // 1 MB
    unsigned long long* abits   = (unsigned long long*)(ws + 28868608); // 2 MB

    hipMemsetAsync(out, 0, 64 * sizeof(float), stream);
    scan_k<<<1024, 256, 0, stream>>>(adj, nbr, deg, abits, feats);
    cra2_k<<<5120, 256, 0, stream>>>(abits, nbr, deg, a3n, side, scnt, feats);
    a4row_k<<<4096, 256, 0, stream>>>(a3n, side, scnt, deg, nbr, feats, e_w, e_b, x0);
    layer_k<<<1024, 256, 0, stream>>>(x0, x1, w1, b1, w2, b2, eps, nbr, deg, out, 0);
    layer_k<<<1024, 256, 0, stream>>>(x1, x0, w1, b1, w2, b2, eps, nbr, deg, out, 1);
    layer_k<<<1024, 256, 0, stream>>>(x0, x1, w1, b1, w2, b2, eps, nbr, deg, out, 2);
}

// Round 16
// 238.128 us; speedup vs baseline: 2.0735x; 1.0139x over previous
//
#include <hip/hip_runtime.h>
#include <hip/hip_bf16.h>
#include <stdint.h>

#define NN 4096

// Round-36:
//  - memset dispatch deleted: scan_k block 0 zeroes out[64] (stream order
//    guarantees completion before layer2's atomics). Dispatches 6 -> 5.
//  - cra2 a3 scatter: 2-deep explicit MLP — both plist reads and both nbr
//    gathers issue before either LDS atomic (the per-thread dependent chain
//    plist->gather->atomic x34 becomes x17 with 2 gathers in flight).
//  - everything else is the proven R15 config: pair-expanded cra2, strided
//    nibble a3, 256-thread a4row (16 cols/thread, uint2), DPP extraction
//    with (val<<6)|lane keys, LDS-staged layer_k.

__device__ __forceinline__ unsigned int wave_umax_bcast(unsigned int v) {
    // full-wave64 max on the VALU via DPP; result broadcast via readlane.
    int x = (int)v;                           // values < 2^22: signed==unsigned
    x = max(x, __builtin_amdgcn_update_dpp(0, x, 0x111, 0xF, 0xF, true)); // row_shr:1
    x = max(x, __builtin_amdgcn_update_dpp(0, x, 0x112, 0xF, 0xF, true)); // row_shr:2
    x = max(x, __builtin_amdgcn_update_dpp(0, x, 0x114, 0xF, 0xF, true)); // row_shr:4
    x = max(x, __builtin_amdgcn_update_dpp(0, x, 0x118, 0xF, 0xF, true)); // row_shr:8
    x = max(x, __builtin_amdgcn_update_dpp(0, x, 0x142, 0xF, 0xF, true)); // row_bcast:15
    x = max(x, __builtin_amdgcn_update_dpp(0, x, 0x143, 0xF, 0xF, true)); // row_bcast:31
    return (unsigned int)__builtin_amdgcn_readlane(x, 63);
}

// ---------------------------------------------------------------------------
// K1: scan_k — one pass over adj per row with float4 loads (16 B/lane).
// Bit layout of abits: word(e) = ((e>>8)<<2)|(e&3), bit(e) = (e>>2)&63.
// Block 0 also zeroes out[64] (replaces the memset dispatch).
// ---------------------------------------------------------------------------
__global__ __launch_bounds__(256) void scan_k(const float* __restrict__ adj,
                                              int* __restrict__ nbr,
                                              int* __restrict__ deg,
                                              unsigned long long* __restrict__ abits,
                                              float* __restrict__ feats,
                                              float* __restrict__ out) {
    __shared__ int nlist[4][64];
    int tid = threadIdx.x;
    int wv = tid >> 6, ln = tid & 63;
    int v = blockIdx.x * 4 + wv;
    if (blockIdx.x == 0 && tid < 64) out[tid] = 0.f;
    size_t rb = (size_t)v * NN;
    int total = 0;
    unsigned long long w0 = 0;
    const float4* row4 = (const float4*)(adj + rb);
    for (int base = 0; base < NN; base += 256) {
        float4 f = row4[(base >> 2) + ln];
        int q4 = (base >> 8) << 2;
        #pragma unroll
        for (int j = 0; j < 4; j++) {
            float vj = (j == 0) ? f.x : (j == 1) ? f.y : (j == 2) ? f.z : f.w;
            unsigned long long m = __ballot(vj > 0.5f);
            if (vj > 0.5f) {
                int pos = total + __popcll(m & ((1ull << ln) - 1ull));
                if (pos < 64) nlist[wv][pos] = base + 4 * ln + j;
            }
            if (ln == q4 + j) w0 = m;
            total += __popcll(m);
        }
    }
    abits[(size_t)v * 64 + ln] = w0;
    int degL = min(total, 64);
    if (ln < degL) nbr[v * 64 + ln] = nlist[wv][ln];
    if (ln == 0) {
        deg[v] = total;
        float degf = (float)total;
        feats[v * 16 + 12] = degf;
        feats[v * 16 + 13] = degf * degf;
        feats[v * 16 + 14] = degf;           // diag(A^2) = deg (symmetric 0/1)
    }
}

// ---------------------------------------------------------------------------
// K2: cra2_k — role-split merged dispatch:
//   blocks [0, 4096):    pair-list -> a3 (LDS, 2-deep-MLP weight-1 scatter)
//                        -> STRIDED nibble row + overflow side-list
//   blocks [4096, 5120): cr_feat from the L2-resident bitmask (4 nodes/block)
// ---------------------------------------------------------------------------
__global__ __launch_bounds__(256) void cra2_k(const unsigned long long* __restrict__ abits,
                                              const int* __restrict__ nbr,
                                              const int* __restrict__ deg,
                                              unsigned int* __restrict__ a3n,
                                              unsigned int* __restrict__ side,
                                              unsigned int* __restrict__ scnt,
                                              float* __restrict__ feats) {
    __shared__ __align__(64) unsigned int smem[NN + 196 + 640];
    int tid = threadIdx.x;
    int bid = blockIdx.x;
    int wv = tid >> 6, ln = tid & 63;

    if (bid < NN) {
        // ------------------- a3 role (pair-expanded) -------------------
        unsigned int* acc   = smem;                     // [4096]
        int* us             = (int*)(smem + NN);        // [64]
        int* dus            = (int*)(smem + NN + 64);   // [64]
        unsigned int* pbase = smem + NN + 128;          // [64] excl prefix of dus
        unsigned int* wsumS = smem + NN + 192;          // [4]
        unsigned int* plist = smem + NN + 196;          // [640] (dgw<<12)|w
        int v = bid;
        uint4 z = {0u, 0u, 0u, 0u};
        #pragma unroll
        for (int i = 0; i < 4; i++) ((uint4*)acc)[tid + 256 * i] = z;
        int dv = min(deg[v], 64);
        if (tid < 64) {
            int u = (tid < dv) ? nbr[v * 64 + tid] : 0;
            us[tid] = u;
            int du = (tid < dv) ? min(deg[u], 64) : 0;
            dus[tid] = du;
            // exclusive prefix of dus across wave 0
            int incl = du;
            #pragma unroll
            for (int off = 1; off < 64; off <<= 1) {
                int n = __shfl_up(incl, off, 64);
                if (tid >= off) incl += n;
            }
            pbase[tid] = (unsigned int)(incl - du);
            if (tid == 63) wsumS[0] = (unsigned int)incl;   // total pair count
        }
        __syncthreads();
        int npair = (int)min(wsumS[0], 640u);
        // fill pair list: entry = w | (min(deg[w],64)<<12); direct writes
        for (int p = tid; p < dv * 64; p += 256) {
            int i = p >> 6, j = p & 63;
            if (j < dus[i]) {
                unsigned int pos = pbase[i] + (unsigned int)j;
                if (pos < 640u) {
                    unsigned int w = (unsigned int)nbr[us[i] * 64 + j];
                    plist[pos] = w | ((unsigned int)min(deg[w], 64) << 12);
                }
            }
        }
        __syncthreads();
        // a3 scatter: acc[x] = sum over pairs (u,w) of A[w,x]; weight == 1.
        // 2-deep MLP: issue both nbr gathers before either atomic.
        int lim64 = ((npair + 1) >> 1) << 6;
        for (int q = tid; q < lim64; q += 512) {
            int s1 = ((q >> 6) << 1) | ((q >> 5) & 1);
            int j1 = q & 31;
            int qb = q + 256;
            int s2 = ((qb >> 6) << 1) | ((qb >> 5) & 1);
            int j2 = qb & 31;
            unsigned int e1 = (s1 < npair) ? plist[s1] : 0u;
            unsigned int e2 = (qb < lim64 && s2 < npair) ? plist[s2] : 0u;
            int d1 = (int)(e1 >> 12), d2 = (int)(e2 >> 12);
            const int* nr1 = nbr + (e1 & 0xFFFu) * 64;
            const int* nr2 = nbr + (e2 & 0xFFFu) * 64;
            int x1 = (j1 < d1) ? nr1[j1] : -1;
            int x2 = (j2 < d2) ? nr2[j2] : -1;
            if (x1 >= 0) atomicAdd(&acc[x1], 1u);
            if (x2 >= 0) atomicAdd(&acc[x2], 1u);
            if (j1 == 31) {
                for (int jj = 32; jj < d1; jj++) atomicAdd(&acc[nr1[jj]], 1u);
            }
            if (j2 == 31) {
                for (int jj = 32; jj < d2; jj++) atomicAdd(&acc[nr2[jj]], 1u);
            }
        }
        __syncthreads();
        // STRIDED nibble emit (word w = cols {w+512k}) + overflow side-list.
        unsigned int wA = 0, wB = 0, ovm = 0;
        #pragma unroll
        for (int k = 0; k < 8; k++) {
            unsigned int a = acc[tid + 512 * k];
            wA |= min(a, 15u) << (4 * k);
            ovm |= (a > 15u ? 1u : 0u) << k;
        }
        #pragma unroll
        for (int k = 0; k < 8; k++) {
            unsigned int a = acc[tid + 256 + 512 * k];
            wB |= min(a, 15u) << (4 * k);
            ovm |= (a > 15u ? 1u : 0u) << (8 + k);
        }
        a3n[(size_t)v * 512 + tid] = wA;
        a3n[(size_t)v * 512 + tid + 256] = wB;
        int lov = __popc(ovm);
        int inc2 = lov;
        #pragma unroll
        for (int off = 1; off < 64; off <<= 1) {
            int n = __shfl_up(inc2, off, 64);
            if (ln >= off) inc2 += n;
        }
        if (ln == 63) wsumS[wv] = (unsigned int)inc2;
        __syncthreads();
        unsigned int wpre2 = 0, totS = 0;
        #pragma unroll
        for (int q = 0; q < 4; q++) {
            unsigned int s = wsumS[q];
            if (q < wv) wpre2 += s;
            totS += s;
        }
        unsigned int pos2 = wpre2 + (unsigned int)(inc2 - lov);
        unsigned int* sideR = side + (size_t)v * 192;
        while (ovm) {
            int i2 = __ffs(ovm) - 1;
            ovm &= ovm - 1;
            unsigned int col = (i2 < 8) ? (unsigned int)(tid + 512 * i2)
                                        : (unsigned int)(tid + 256 + 512 * (i2 - 8));
            unsigned int a = acc[col];
            if (pos2 < 192u) sideR[pos2] = ((a - 15u) << 16) | col;
            pos2++;
        }
        if (tid == 0) scnt[v] = min(totS, 192u);
    } else {
        // ------------------- cr role -------------------
        unsigned long long* rows = (unsigned long long*)smem;   // [4][64], 2 KB
        int* mems = (int*)(smem + 1024);                        // [4][64], 1 KB
        int v = (bid - NN) * 4 + wv;

        int dv = deg[v];
        int degL = min(dv, 64);
        int c = min(dv + 1, 64);

        int nl = (ln < degL) ? nbr[v * 64 + ln] : 0;
        int isless = (ln < degL && nl < v) ? 1 : 0;
        int pos = isless;
        #pragma unroll
        for (int off = 32; off; off >>= 1) pos += __shfl_xor(pos, off, 64);

        int mem = 0;
        if (ln < c) {
            if (ln < pos)       mem = nl;
            else if (ln == pos) mem = v;
            else                mem = nbr[v * 64 + ln - 1];
        }
        mems[wv * 64 + ln] = mem;
        __syncthreads();

        unsigned long long mask = 0ull;
        {
            const unsigned long long* rowb = abits + (size_t)mem * 64;
            for (int j = 0; j < c; j++) {
                int mj = mems[wv * 64 + j];
                unsigned long long w = rowb[((mj >> 8) << 2) | (mj & 3)];
                mask |= ((w >> ((mj >> 2) & 63)) & 1ull) << j;
            }
        }
        if (ln >= c) mask = 0ull;
        rows[wv * 64 + ln] = mask;
        __syncthreads();

        int tpart = 0;
        float epart = 0.f, wpart = 0.f;
        if (ln < c) {
            unsigned long long mm = mask;
            while (mm) {
                int j = __ffsll(mm) - 1;
                mm &= mm - 1;
                tpart += __popcll(mask & rows[wv * 64 + j]);
            }
            if (ln != pos) {
                int cn = __popcll(rows[wv * 64 + pos] & mask);
                float D2 = (float)cn + 1.0f;
                epart = D2;
                wpart = D2 * (D2 - 1.0f) * 0.5f;
            }
        }
        float es = epart, wsum2 = wpart;
        int ts = tpart;
        #pragma unroll
        for (int off = 32; off; off >>= 1) {
            es += __shfl_xor(es, off, 64);
            wsum2 += __shfl_xor(wsum2, off, 64);
            ts += __shfl_xor(ts, off, 64);
        }

        if (ln == 0) {
            float degf = (float)dv;
            float k = degf + 1.0f;
            float E = 0.5f * (es + degf);
            float W = wsum2 + degf * (degf - 1.0f) * 0.5f;
            float T = (float)ts / 6.0f;
            float f3 = T;
            float f2 = W - 3.0f * T;
            float f1 = E * (k - 2.0f) - 2.0f * f2 - 3.0f * f3;
            float tot2 = k * (k - 1.0f) * (k - 2.0f) / 6.0f;
            float f0 = tot2 - f1 - f2 - f3;
            if (k < 3.0f) { f0 = f1 = f2 = f3 = 0.f; }
            float s = f0 + f1 + f2 + f3 + 1e-10f;
            feats[v * 16 + 0] = f0 / s;
            feats[v * 16 + 1] = f1 / s;
            feats[v * 16 + 2] = f2 / s;
            feats[v * 16 + 3] = f3 / s;
        }
    }
}

// ---------------------------------------------------------------------------
// K4: fused a4-row (register-gather over strided nibble a3 + side-list) +
// top-8 + embedding. 256 threads, 2 owned words (16 cols) per thread via
// uint2 loads; DPP max-reduce extraction with (val<<6)|lane keys.
// ---------------------------------------------------------------------------
__global__ __launch_bounds__(256) void a4row_k(const unsigned int* __restrict__ a3n,
                                               const unsigned int* __restrict__ side,
                                               const unsigned int* __restrict__ scnt,
                                               const int* __restrict__ deg,
                                               const int* __restrict__ nbr,
                                               const float* __restrict__ feats,
                                               const float* __restrict__ e_w,
                                               const float* __restrict__ e_b,
                                               float* __restrict__ x0) {
    __shared__ unsigned int sacc[NN];        // 16 KB u32 side accumulator
    __shared__ unsigned int sbase[64];       // u*512 (word base of a3 row)
    __shared__ unsigned int sbs[64];         // u*192 (side base)
    __shared__ unsigned int sS[64];          // side counts
    __shared__ unsigned int wtops[32];
    int tid = threadIdx.x;
    int wv = tid >> 6, ln = tid & 63;
    int v = blockIdx.x;

    {
        uint4 z = {0u, 0u, 0u, 0u};
        #pragma unroll
        for (int i = 0; i < 4; i++) ((uint4*)sacc)[tid + 256 * i] = z;
    }
    int dvv = min(deg[v], 64);
    if (tid < dvv) {
        unsigned int u = (unsigned int)nbr[v * 64 + tid];
        sbase[tid] = u * 512u;
        sbs[tid]   = u * 192u;
        sS[tid]    = scnt[u];
    }
    __syncthreads();

    // side scatter (few hundred entries; hides under the base loop)
    for (int i = wv; i < dvv; i += 4) {
        int ns = (int)sS[i];
        const unsigned int* sp = side + sbs[i];
        for (int g2 = ln; g2 < ns; g2 += 64) {
            unsigned int e = sp[g2];
            atomicAdd(&sacc[e & 0xFFFu], e >> 16);
        }
    }

    // base: register gather-accumulate, 2 words per thread (uint2 loads)
    unsigned int aE0 = 0, aO0 = 0, aE1 = 0, aO1 = 0;
    unsigned int SE00 = 0, SE01 = 0, SO00 = 0, SO01 = 0;
    unsigned int SE10 = 0, SE11 = 0, SO10 = 0, SO11 = 0;
    for (int s0 = 0; s0 < dvv; s0 += 16) {
        int se = min(s0 + 16, dvv);
        for (int s = s0; s < se; s++) {
            uint2 W = ((const uint2*)(a3n + sbase[s]))[tid];
            aE0 += W.x & 0x0F0F0F0Fu;
            aO0 += (W.x >> 4) & 0x0F0F0F0Fu;
            aE1 += W.y & 0x0F0F0F0Fu;
            aO1 += (W.y >> 4) & 0x0F0F0F0Fu;
        }
        SE00 += __builtin_amdgcn_perm(0u, aE0, 0x0c010c00u);  // {b0,b1} as u16
        SE01 += __builtin_amdgcn_perm(0u, aE0, 0x0c030c02u);  // {b2,b3}
        SO00 += __builtin_amdgcn_perm(0u, aO0, 0x0c010c00u);
        SO01 += __builtin_amdgcn_perm(0u, aO0, 0x0c030c02u);
        SE10 += __builtin_amdgcn_perm(0u, aE1, 0x0c010c00u);
        SE11 += __builtin_amdgcn_perm(0u, aE1, 0x0c030c02u);
        SO10 += __builtin_amdgcn_perm(0u, aO1, 0x0c010c00u);
        SO11 += __builtin_amdgcn_perm(0u, aO1, 0x0c030c02u);
        aE0 = 0; aO0 = 0; aE1 = 0; aO1 = 0;
    }
    __syncthreads();

    // merge side sums with register base sums.
    unsigned int vv[16];
    {
        uint2 u0 = ((uint2*)sacc)[tid];
        uint2 u1 = ((uint2*)sacc)[tid + 256];
        uint2 u2 = ((uint2*)sacc)[tid + 512];
        uint2 u3 = ((uint2*)sacc)[tid + 768];
        uint2 u4 = ((uint2*)sacc)[tid + 1024];
        uint2 u5 = ((uint2*)sacc)[tid + 1280];
        uint2 u6 = ((uint2*)sacc)[tid + 1536];
        uint2 u7 = ((uint2*)sacc)[tid + 1792];
        vv[0]  = (SE00 & 0xFFFFu) + u0.x;  vv[8]  = (SE10 & 0xFFFFu) + u0.y;
        vv[1]  = (SO00 & 0xFFFFu) + u1.x;  vv[9]  = (SO10 & 0xFFFFu) + u1.y;
        vv[2]  = (SE00 >> 16)     + u2.x;  vv[10] = (SE10 >> 16)     + u2.y;
        vv[3]  = (SO00 >> 16)     + u3.x;  vv[11] = (SO10 >> 16)     + u3.y;
        vv[4]  = (SE01 & 0xFFFFu) + u4.x;  vv[12] = (SE11 & 0xFFFFu) + u4.y;
        vv[5]  = (SO01 & 0xFFFFu) + u5.x;  vv[13] = (SO11 & 0xFFFFu) + u5.y;
        vv[6]  = (SE01 >> 16)     + u6.x;  vv[14] = (SE11 >> 16)     + u6.y;
        vv[7]  = (SO01 >> 16)     + u7.x;  vv[15] = (SO11 >> 16)     + u7.y;
    }

    // per-thread top-8 over the 16 owned columns
    unsigned int best[8];
    #pragma unroll
    for (int q = 0; q < 8; q++) best[q] = 0u;
    #pragma unroll
    for (int m = 0; m < 16; m++) {
        unsigned int val = vv[m];
        if (val > best[7]) {
            best[7] = val;
            #pragma unroll
            for (int s = 7; s > 0; s--) {
                if (best[s] > best[s - 1]) {
                    unsigned int t2 = best[s - 1]; best[s - 1] = best[s]; best[s] = t2;
                } else break;
            }
        }
    }

    // per-wave extract of 8 maxima (DPP max-reduce on (val<<6)|lane keys)
    unsigned int wave_val = 0u;
    #pragma unroll
    for (int r = 0; r < 8; r++) {
        unsigned int kmax = wave_umax_bcast((best[0] << 6) | (unsigned int)ln);
        if (ln == (int)(kmax & 63u)) {
            #pragma unroll
            for (int s = 0; s < 7; s++) best[s] = best[s + 1];
            best[7] = 0u;
        }
        if (ln == r) wave_val = kmax >> 6;
    }
    if (ln < 8) wtops[wv * 8 + ln] = wave_val;
    __syncthreads();

    // wave 0: merge 32 candidates, then fused embedding
    if (wv == 0) {
        unsigned int cand = (ln < 32) ? wtops[ln] : 0u;
        unsigned int myv = 0u;
        #pragma unroll
        for (int r = 0; r < 8; r++) {
            unsigned int kmax = wave_umax_bcast((cand << 6) | (unsigned int)ln);
            if (ln == (int)(kmax & 63u)) cand = 0u;
            if (ln == r) myv = kmax >> 6;
        }
        int d = ln;
        float s = e_b[d];
        s += feats[v * 16 + 0]  * e_w[0 * 64 + d];
        s += feats[v * 16 + 1]  * e_w[1 * 64 + d];
        s += feats[v * 16 + 2]  * e_w[2 * 64 + d];
        s += feats[v * 16 + 3]  * e_w[3 * 64 + d];
        #pragma unroll
        for (int j = 0; j < 8; j++) {
            float mj = (float)(unsigned int)__shfl((int)myv, j, 64);
            s += mj * e_w[(4 + j) * 64 + d];
        }
        s += feats[v * 16 + 12] * e_w[12 * 64 + d];
        s += feats[v * 16 + 13] * e_w[13 * 64 + d];
        s += feats[v * 16 + 14] * e_w[14 * 64 + d];
        x0[(size_t)v * 64 + d] = s;
    }
}

// ---------------------------------------------------------------------------
// K5: one GNN layer, weights LDS-staged. For li==2, accumulate block column
// sums directly into out[64] via fp32 atomics.
// ---------------------------------------------------------------------------
__global__ __launch_bounds__(256) void layer_k(const float* __restrict__ xin,
                                               float* __restrict__ xout,
                                               const float* __restrict__ w1,
                                               const float* __restrict__ b1,
                                               const float* __restrict__ w2,
                                               const float* __restrict__ b2,
                                               const float* __restrict__ eps,
                                               const int* __restrict__ nbr,
                                               const int* __restrict__ deg,
                                               float* __restrict__ out,
                                               int li) {
    __shared__ float wL[4096];                // 16 KB, reused for w1 then w2
    __shared__ float h[4][64], t[4][64];
    int tid = threadIdx.x;
    int wv = tid >> 6, d = tid & 63;
    int v = blockIdx.x * 4 + wv;

    // stage w1 (coalesced float4)
    {
        const float4* src = (const float4*)(w1 + li * 4096);
        #pragma unroll
        for (int i = 0; i < 4; i++) ((float4*)wL)[tid + 256 * i] = src[tid + 256 * i];
    }

    float xv = xin[(size_t)v * 64 + d];
    int dv = min(deg[v], 64);
    const int* nl = nbr + v * 64;
    float agg = 0.f;
    int j = 0;
    for (; j + 4 <= dv; j += 4) {
        int n0 = nl[j], n1 = nl[j + 1], n2 = nl[j + 2], n3 = nl[j + 3];
        float a0 = xin[(size_t)n0 * 64 + d];
        float a1 = xin[(size_t)n1 * 64 + d];
        float a2v = xin[(size_t)n2 * 64 + d];
        float a3 = xin[(size_t)n3 * 64 + d];
        agg += (a0 + a1) + (a2v + a3);
    }
    for (; j < dv; j++) agg += xin[(size_t)nl[j] * 64 + d];
    float hv = (1.0f + eps[li]) * xv + agg;
    h[wv][d] = hv;
    __syncthreads();

    float s = b1[li * 64 + d];
    #pragma unroll 8
    for (int k = 0; k < 64; k++) s += h[wv][k] * wL[k * 64 + d];
    s = fmaxf(s, 0.f);
    t[wv][d] = s;
    __syncthreads();

    // stage w2 (reuse wL)
    {
        const float4* src = (const float4*)(w2 + li * 4096);
        #pragma unroll
        for (int i = 0; i < 4; i++) ((float4*)wL)[tid + 256 * i] = src[tid + 256 * i];
    }
    __syncthreads();

    float o = b2[li * 64 + d];
    #pragma unroll 8
    for (int k = 0; k < 64; k++) o += t[wv][k] * wL[k * 64 + d];
    if (li == 2) {
        h[wv][d] = o;
        __syncthreads();
        if (wv == 0)
            atomicAdd(&out[d], (h[0][d] + h[1][d]) + (h[2][d] + h[3][d]));
    } else {
        xout[(size_t)v * 64 + d] = o;
    }
}

// ---------------------------------------------------------------------------
extern "C" void kernel_launch(void* const* d_in, const int* in_sizes, int n_in,
                              void* d_out, int out_size, void* d_ws, size_t ws_size,
                              hipStream_t stream) {
    const float* adj = (const float*)d_in[0];
    const float* e_w = (const float*)d_in[1];
    const float* e_b = (const float*)d_in[2];
    const float* w1  = (const float*)d_in[3];
    const float* b1  = (const float*)d_in[4];
    const float* w2  = (const float*)d_in[5];
    const float* b2  = (const float*)d_in[6];
    const float* eps = (const float*)d_in[7];
    float* out = (float*)d_out;

    char* ws = (char*)d_ws;
    unsigned int*       a3n     = (unsigned int*)(ws);                  // 8 MB nibble a3
    unsigned int*       side    = (unsigned int*)(ws + 8388608);        // 3 MB side-list
    unsigned int*       scnt    = (unsigned int*)(ws + 11534336);       // 16 KB
    int*                nbr     = (int*)(ws + 25165824);                // 1 MB
    int*                deg     = (int*)(ws + 26214400);                // 16 KB
    float*              feats   = (float*)(ws + 26247168);              // 256 KB
    float*              x0      = (float*)(ws + 26509312);              // 1 MB
    float*              x1      = (float*)(ws + 27557888);              // 1 MB
    unsigned long long* abits   = (unsigned long long*)(ws + 28868608); // 2 MB

    scan_k<<<1024, 256, 0, stream>>>(adj, nbr, deg, abits, feats, out);
    cra2_k<<<5120, 256, 0, stream>>>(abits, nbr, deg, a3n, side, scnt, feats);
    a4row_k<<<4096, 256, 0, stream>>>(a3n, side, scnt, deg, nbr, feats, e_w, e_b, x0);
    layer_k<<<1024, 256, 0, stream>>>(x0, x1, w1, b1, w2, b2, eps, nbr, deg, out, 0);
    layer_k<<<1024, 256, 0, stream>>>(x1, x0, w1, b1, w2, b2, eps, nbr, deg, out, 1);
    layer_k<<<1024, 256, 0, stream>>>(x0, x1, w1, b1, w2, b2, eps, nbr, deg, out, 2);
}

// Round 17
// 226.573 us; speedup vs baseline: 2.1792x; 1.0510x over previous
//
#include <hip/hip_runtime.h>
#include <hip/hip_bf16.h>
#include <stdint.h>

#define NN 4096

// Round-37:
//  - a4row top-8 insert is BRANCHLESS (max/min carry chain, 16 ops/value):
//    the old insertion sort's data-dependent breaks diverged across 64 lanes
//    and cost ~700 instr/thread — the largest VALU block in the kernel.
//  - cra2 a3 scatter: 4-deep explicit MLP (4 plist reads + 4 nbr gathers in
//    flight before the atomics).
//  - everything else is the R16 config (238.1 us): pair-expanded cra2,
//    strided nibble a3, 256-thread a4row (16 cols/thread, uint2), DPP
//    extraction with (val<<6)|lane keys, LDS-staged layer_k, 5 dispatches.

__device__ __forceinline__ unsigned int wave_umax_bcast(unsigned int v) {
    // full-wave64 max on the VALU via DPP; result broadcast via readlane.
    int x = (int)v;                           // values < 2^22: signed==unsigned
    x = max(x, __builtin_amdgcn_update_dpp(0, x, 0x111, 0xF, 0xF, true)); // row_shr:1
    x = max(x, __builtin_amdgcn_update_dpp(0, x, 0x112, 0xF, 0xF, true)); // row_shr:2
    x = max(x, __builtin_amdgcn_update_dpp(0, x, 0x114, 0xF, 0xF, true)); // row_shr:4
    x = max(x, __builtin_amdgcn_update_dpp(0, x, 0x118, 0xF, 0xF, true)); // row_shr:8
    x = max(x, __builtin_amdgcn_update_dpp(0, x, 0x142, 0xF, 0xF, true)); // row_bcast:15
    x = max(x, __builtin_amdgcn_update_dpp(0, x, 0x143, 0xF, 0xF, true)); // row_bcast:31
    return (unsigned int)__builtin_amdgcn_readlane(x, 63);
}

// ---------------------------------------------------------------------------
// K1: scan_k — one pass over adj per row with float4 loads (16 B/lane).
// Bit layout of abits: word(e) = ((e>>8)<<2)|(e&3), bit(e) = (e>>2)&63.
// Block 0 also zeroes out[64] (replaces the memset dispatch).
// ---------------------------------------------------------------------------
__global__ __launch_bounds__(256) void scan_k(const float* __restrict__ adj,
                                              int* __restrict__ nbr,
                                              int* __restrict__ deg,
                                              unsigned long long* __restrict__ abits,
                                              float* __restrict__ feats,
                                              float* __restrict__ out) {
    __shared__ int nlist[4][64];
    int tid = threadIdx.x;
    int wv = tid >> 6, ln = tid & 63;
    int v = blockIdx.x * 4 + wv;
    if (blockIdx.x == 0 && tid < 64) out[tid] = 0.f;
    size_t rb = (size_t)v * NN;
    int total = 0;
    unsigned long long w0 = 0;
    const float4* row4 = (const float4*)(adj + rb);
    for (int base = 0; base < NN; base += 256) {
        float4 f = row4[(base >> 2) + ln];
        int q4 = (base >> 8) << 2;
        #pragma unroll
        for (int j = 0; j < 4; j++) {
            float vj = (j == 0) ? f.x : (j == 1) ? f.y : (j == 2) ? f.z : f.w;
            unsigned long long m = __ballot(vj > 0.5f);
            if (vj > 0.5f) {
                int pos = total + __popcll(m & ((1ull << ln) - 1ull));
                if (pos < 64) nlist[wv][pos] = base + 4 * ln + j;
            }
            if (ln == q4 + j) w0 = m;
            total += __popcll(m);
        }
    }
    abits[(size_t)v * 64 + ln] = w0;
    int degL = min(total, 64);
    if (ln < degL) nbr[v * 64 + ln] = nlist[wv][ln];
    if (ln == 0) {
        deg[v] = total;
        float degf = (float)total;
        feats[v * 16 + 12] = degf;
        feats[v * 16 + 13] = degf * degf;
        feats[v * 16 + 14] = degf;           // diag(A^2) = deg (symmetric 0/1)
    }
}

// ---------------------------------------------------------------------------
// K2: cra2_k — role-split merged dispatch:
//   blocks [0, 4096):    pair-list -> a3 (LDS, 4-deep-MLP weight-1 scatter)
//                        -> STRIDED nibble row + overflow side-list
//   blocks [4096, 5120): cr_feat from the L2-resident bitmask (4 nodes/block)
// ---------------------------------------------------------------------------
__global__ __launch_bounds__(256) void cra2_k(const unsigned long long* __restrict__ abits,
                                              const int* __restrict__ nbr,
                                              const int* __restrict__ deg,
                                              unsigned int* __restrict__ a3n,
                                              unsigned int* __restrict__ side,
                                              unsigned int* __restrict__ scnt,
                                              float* __restrict__ feats) {
    __shared__ __align__(64) unsigned int smem[NN + 196 + 640];
    int tid = threadIdx.x;
    int bid = blockIdx.x;
    int wv = tid >> 6, ln = tid & 63;

    if (bid < NN) {
        // ------------------- a3 role (pair-expanded) -------------------
        unsigned int* acc   = smem;                     // [4096]
        int* us             = (int*)(smem + NN);        // [64]
        int* dus            = (int*)(smem + NN + 64);   // [64]
        unsigned int* pbase = smem + NN + 128;          // [64] excl prefix of dus
        unsigned int* wsumS = smem + NN + 192;          // [4]
        unsigned int* plist = smem + NN + 196;          // [640] (dgw<<12)|w
        int v = bid;
        uint4 z = {0u, 0u, 0u, 0u};
        #pragma unroll
        for (int i = 0; i < 4; i++) ((uint4*)acc)[tid + 256 * i] = z;
        int dv = min(deg[v], 64);
        if (tid < 64) {
            int u = (tid < dv) ? nbr[v * 64 + tid] : 0;
            us[tid] = u;
            int du = (tid < dv) ? min(deg[u], 64) : 0;
            dus[tid] = du;
            // exclusive prefix of dus across wave 0
            int incl = du;
            #pragma unroll
            for (int off = 1; off < 64; off <<= 1) {
                int n = __shfl_up(incl, off, 64);
                if (tid >= off) incl += n;
            }
            pbase[tid] = (unsigned int)(incl - du);
            if (tid == 63) wsumS[0] = (unsigned int)incl;   // total pair count
        }
        __syncthreads();
        int npair = (int)min(wsumS[0], 640u);
        // fill pair list: entry = w | (min(deg[w],64)<<12); direct writes
        for (int p = tid; p < dv * 64; p += 256) {
            int i = p >> 6, j = p & 63;
            if (j < dus[i]) {
                unsigned int pos = pbase[i] + (unsigned int)j;
                if (pos < 640u) {
                    unsigned int w = (unsigned int)nbr[us[i] * 64 + j];
                    plist[pos] = w | ((unsigned int)min(deg[w], 64) << 12);
                }
            }
        }
        __syncthreads();
        // a3 scatter: acc[x] = sum over pairs (u,w) of A[w,x]; weight == 1.
        // 4-deep MLP: issue 4 nbr gathers before any atomic.
        int lim64 = ((npair + 1) >> 1) << 6;
        for (int q = tid; q < lim64; q += 1024) {
            int qa = q, qb = q + 256, qc = q + 512, qd = q + 768;
            int sa = ((qa >> 6) << 1) | ((qa >> 5) & 1), ja = qa & 31;
            int sb = ((qb >> 6) << 1) | ((qb >> 5) & 1), jb = qb & 31;
            int sc = ((qc >> 6) << 1) | ((qc >> 5) & 1), jc = qc & 31;
            int sd = ((qd >> 6) << 1) | ((qd >> 5) & 1), jd = qd & 31;
            unsigned int ea = (sa < npair) ? plist[sa] : 0u;
            unsigned int eb = (qb < lim64 && sb < npair) ? plist[sb] : 0u;
            unsigned int ec = (qc < lim64 && sc < npair) ? plist[sc] : 0u;
            unsigned int ed = (qd < lim64 && sd < npair) ? plist[sd] : 0u;
            int da = (int)(ea >> 12), db = (int)(eb >> 12);
            int dc = (int)(ec >> 12), dd = (int)(ed >> 12);
            const int* na = nbr + (ea & 0xFFFu) * 64;
            const int* nb = nbr + (eb & 0xFFFu) * 64;
            const int* nc = nbr + (ec & 0xFFFu) * 64;
            const int* nd = nbr + (ed & 0xFFFu) * 64;
            int xa = (ja < da) ? na[ja] : -1;
            int xb = (jb < db) ? nb[jb] : -1;
            int xc = (jc < dc) ? nc[jc] : -1;
            int xd = (jd < dd) ? nd[jd] : -1;
            if (xa >= 0) atomicAdd(&acc[xa], 1u);
            if (xb >= 0) atomicAdd(&acc[xb], 1u);
            if (xc >= 0) atomicAdd(&acc[xc], 1u);
            if (xd >= 0) atomicAdd(&acc[xd], 1u);
            if (ja == 31) { for (int jj = 32; jj < da; jj++) atomicAdd(&acc[na[jj]], 1u); }
            if (jb == 31) { for (int jj = 32; jj < db; jj++) atomicAdd(&acc[nb[jj]], 1u); }
            if (jc == 31) { for (int jj = 32; jj < dc; jj++) atomicAdd(&acc[nc[jj]], 1u); }
            if (jd == 31) { for (int jj = 32; jj < dd; jj++) atomicAdd(&acc[nd[jj]], 1u); }
        }
        __syncthreads();
        // STRIDED nibble emit (word w = cols {w+512k}) + overflow side-list.
        unsigned int wA = 0, wB = 0, ovm = 0;
        #pragma unroll
        for (int k = 0; k < 8; k++) {
            unsigned int a = acc[tid + 512 * k];
            wA |= min(a, 15u) << (4 * k);
            ovm |= (a > 15u ? 1u : 0u) << k;
        }
        #pragma unroll
        for (int k = 0; k < 8; k++) {
            unsigned int a = acc[tid + 256 + 512 * k];
            wB |= min(a, 15u) << (4 * k);
            ovm |= (a > 15u ? 1u : 0u) << (8 + k);
        }
        a3n[(size_t)v * 512 + tid] = wA;
        a3n[(size_t)v * 512 + tid + 256] = wB;
        int lov = __popc(ovm);
        int inc2 = lov;
        #pragma unroll
        for (int off = 1; off < 64; off <<= 1) {
            int n = __shfl_up(inc2, off, 64);
            if (ln >= off) inc2 += n;
        }
        if (ln == 63) wsumS[wv] = (unsigned int)inc2;
        __syncthreads();
        unsigned int wpre2 = 0, totS = 0;
        #pragma unroll
        for (int q = 0; q < 4; q++) {
            unsigned int s = wsumS[q];
            if (q < wv) wpre2 += s;
            totS += s;
        }
        unsigned int pos2 = wpre2 + (unsigned int)(inc2 - lov);
        unsigned int* sideR = side + (size_t)v * 192;
        while (ovm) {
            int i2 = __ffs(ovm) - 1;
            ovm &= ovm - 1;
            unsigned int col = (i2 < 8) ? (unsigned int)(tid + 512 * i2)
                                        : (unsigned int)(tid + 256 + 512 * (i2 - 8));
            unsigned int a = acc[col];
            if (pos2 < 192u) sideR[pos2] = ((a - 15u) << 16) | col;
            pos2++;
        }
        if (tid == 0) scnt[v] = min(totS, 192u);
    } else {
        // ------------------- cr role -------------------
        unsigned long long* rows = (unsigned long long*)smem;   // [4][64], 2 KB
        int* mems = (int*)(smem + 1024);                        // [4][64], 1 KB
        int v = (bid - NN) * 4 + wv;

        int dv = deg[v];
        int degL = min(dv, 64);
        int c = min(dv + 1, 64);

        int nl = (ln < degL) ? nbr[v * 64 + ln] : 0;
        int isless = (ln < degL && nl < v) ? 1 : 0;
        int pos = isless;
        #pragma unroll
        for (int off = 32; off; off >>= 1) pos += __shfl_xor(pos, off, 64);

        int mem = 0;
        if (ln < c) {
            if (ln < pos)       mem = nl;
            else if (ln == pos) mem = v;
            else                mem = nbr[v * 64 + ln - 1];
        }
        mems[wv * 64 + ln] = mem;
        __syncthreads();

        unsigned long long mask = 0ull;
        {
            const unsigned long long* rowb = abits + (size_t)mem * 64;
            for (int j = 0; j < c; j++) {
                int mj = mems[wv * 64 + j];
                unsigned long long w = rowb[((mj >> 8) << 2) | (mj & 3)];
                mask |= ((w >> ((mj >> 2) & 63)) & 1ull) << j;
            }
        }
        if (ln >= c) mask = 0ull;
        rows[wv * 64 + ln] = mask;
        __syncthreads();

        int tpart = 0;
        float epart = 0.f, wpart = 0.f;
        if (ln < c) {
            unsigned long long mm = mask;
            while (mm) {
                int j = __ffsll(mm) - 1;
                mm &= mm - 1;
                tpart += __popcll(mask & rows[wv * 64 + j]);
            }
            if (ln != pos) {
                int cn = __popcll(rows[wv * 64 + pos] & mask);
                float D2 = (float)cn + 1.0f;
                epart = D2;
                wpart = D2 * (D2 - 1.0f) * 0.5f;
            }
        }
        float es = epart, wsum2 = wpart;
        int ts = tpart;
        #pragma unroll
        for (int off = 32; off; off >>= 1) {
            es += __shfl_xor(es, off, 64);
            wsum2 += __shfl_xor(wsum2, off, 64);
            ts += __shfl_xor(ts, off, 64);
        }

        if (ln == 0) {
            float degf = (float)dv;
            float k = degf + 1.0f;
            float E = 0.5f * (es + degf);
            float W = wsum2 + degf * (degf - 1.0f) * 0.5f;
            float T = (float)ts / 6.0f;
            float f3 = T;
            float f2 = W - 3.0f * T;
            float f1 = E * (k - 2.0f) - 2.0f * f2 - 3.0f * f3;
            float tot2 = k * (k - 1.0f) * (k - 2.0f) / 6.0f;
            float f0 = tot2 - f1 - f2 - f3;
            if (k < 3.0f) { f0 = f1 = f2 = f3 = 0.f; }
            float s = f0 + f1 + f2 + f3 + 1e-10f;
            feats[v * 16 + 0] = f0 / s;
            feats[v * 16 + 1] = f1 / s;
            feats[v * 16 + 2] = f2 / s;
            feats[v * 16 + 3] = f3 / s;
        }
    }
}

// ---------------------------------------------------------------------------
// K4: fused a4-row (register-gather over strided nibble a3 + side-list) +
// top-8 + embedding. 256 threads, 2 owned words (16 cols) per thread via
// uint2 loads; BRANCHLESS top-8 insert; DPP extraction ((val<<6)|lane keys).
// ---------------------------------------------------------------------------
__global__ __launch_bounds__(256) void a4row_k(const unsigned int* __restrict__ a3n,
                                               const unsigned int* __restrict__ side,
                                               const unsigned int* __restrict__ scnt,
                                               const int* __restrict__ deg,
                                               const int* __restrict__ nbr,
                                               const float* __restrict__ feats,
                                               const float* __restrict__ e_w,
                                               const float* __restrict__ e_b,
                                               float* __restrict__ x0) {
    __shared__ unsigned int sacc[NN];        // 16 KB u32 side accumulator
    __shared__ unsigned int sbase[64];       // u*512 (word base of a3 row)
    __shared__ unsigned int sbs[64];         // u*192 (side base)
    __shared__ unsigned int sS[64];          // side counts
    __shared__ unsigned int wtops[32];
    int tid = threadIdx.x;
    int wv = tid >> 6, ln = tid & 63;
    int v = blockIdx.x;

    {
        uint4 z = {0u, 0u, 0u, 0u};
        #pragma unroll
        for (int i = 0; i < 4; i++) ((uint4*)sacc)[tid + 256 * i] = z;
    }
    int dvv = min(deg[v], 64);
    if (tid < dvv) {
        unsigned int u = (unsigned int)nbr[v * 64 + tid];
        sbase[tid] = u * 512u;
        sbs[tid]   = u * 192u;
        sS[tid]    = scnt[u];
    }
    __syncthreads();

    // side scatter (few hundred entries; hides under the base loop)
    for (int i = wv; i < dvv; i += 4) {
        int ns = (int)sS[i];
        const unsigned int* sp = side + sbs[i];
        for (int g2 = ln; g2 < ns; g2 += 64) {
            unsigned int e = sp[g2];
            atomicAdd(&sacc[e & 0xFFFu], e >> 16);
        }
    }

    // base: register gather-accumulate, 2 words per thread (uint2 loads)
    unsigned int aE0 = 0, aO0 = 0, aE1 = 0, aO1 = 0;
    unsigned int SE00 = 0, SE01 = 0, SO00 = 0, SO01 = 0;
    unsigned int SE10 = 0, SE11 = 0, SO10 = 0, SO11 = 0;
    for (int s0 = 0; s0 < dvv; s0 += 16) {
        int se = min(s0 + 16, dvv);
        for (int s = s0; s < se; s++) {
            uint2 W = ((const uint2*)(a3n + sbase[s]))[tid];
            aE0 += W.x & 0x0F0F0F0Fu;
            aO0 += (W.x >> 4) & 0x0F0F0F0Fu;
            aE1 += W.y & 0x0F0F0F0Fu;
            aO1 += (W.y >> 4) & 0x0F0F0F0Fu;
        }
        SE00 += __builtin_amdgcn_perm(0u, aE0, 0x0c010c00u);  // {b0,b1} as u16
        SE01 += __builtin_amdgcn_perm(0u, aE0, 0x0c030c02u);  // {b2,b3}
        SO00 += __builtin_amdgcn_perm(0u, aO0, 0x0c010c00u);
        SO01 += __builtin_amdgcn_perm(0u, aO0, 0x0c030c02u);
        SE10 += __builtin_amdgcn_perm(0u, aE1, 0x0c010c00u);
        SE11 += __builtin_amdgcn_perm(0u, aE1, 0x0c030c02u);
        SO10 += __builtin_amdgcn_perm(0u, aO1, 0x0c010c00u);
        SO11 += __builtin_amdgcn_perm(0u, aO1, 0x0c030c02u);
        aE0 = 0; aO0 = 0; aE1 = 0; aO1 = 0;
    }
    __syncthreads();

    // merge side sums with register base sums.
    unsigned int vv[16];
    {
        uint2 u0 = ((uint2*)sacc)[tid];
        uint2 u1 = ((uint2*)sacc)[tid + 256];
        uint2 u2 = ((uint2*)sacc)[tid + 512];
        uint2 u3 = ((uint2*)sacc)[tid + 768];
        uint2 u4 = ((uint2*)sacc)[tid + 1024];
        uint2 u5 = ((uint2*)sacc)[tid + 1280];
        uint2 u6 = ((uint2*)sacc)[tid + 1536];
        uint2 u7 = ((uint2*)sacc)[tid + 1792];
        vv[0]  = (SE00 & 0xFFFFu) + u0.x;  vv[8]  = (SE10 & 0xFFFFu) + u0.y;
        vv[1]  = (SO00 & 0xFFFFu) + u1.x;  vv[9]  = (SO10 & 0xFFFFu) + u1.y;
        vv[2]  = (SE00 >> 16)     + u2.x;  vv[10] = (SE10 >> 16)     + u2.y;
        vv[3]  = (SO00 >> 16)     + u3.x;  vv[11] = (SO10 >> 16)     + u3.y;
        vv[4]  = (SE01 & 0xFFFFu) + u4.x;  vv[12] = (SE11 & 0xFFFFu) + u4.y;
        vv[5]  = (SO01 & 0xFFFFu) + u5.x;  vv[13] = (SO11 & 0xFFFFu) + u5.y;
        vv[6]  = (SE01 >> 16)     + u6.x;  vv[14] = (SE11 >> 16)     + u6.y;
        vv[7]  = (SO01 >> 16)     + u7.x;  vv[15] = (SO11 >> 16)     + u7.y;
    }

    // per-thread top-8 over the 16 owned columns — BRANCHLESS carry chain:
    // best[] stays sorted descending; each insert is 8 max + 8 min.
    unsigned int best[8];
    #pragma unroll
    for (int q = 0; q < 8; q++) best[q] = 0u;
    #pragma unroll
    for (int m = 0; m < 16; m++) {
        unsigned int carry = vv[m];
        #pragma unroll
        for (int s = 0; s < 8; s++) {
            unsigned int hi = max(best[s], carry);
            carry = min(best[s], carry);
            best[s] = hi;
        }
    }

    // per-wave extract of 8 maxima (DPP max-reduce on (val<<6)|lane keys)
    unsigned int wave_val = 0u;
    #pragma unroll
    for (int r = 0; r < 8; r++) {
        unsigned int kmax = wave_umax_bcast((best[0] << 6) | (unsigned int)ln);
        if (ln == (int)(kmax & 63u)) {
            #pragma unroll
            for (int s = 0; s < 7; s++) best[s] = best[s + 1];
            best[7] = 0u;
        }
        if (ln == r) wave_val = kmax >> 6;
    }
    if (ln < 8) wtops[wv * 8 + ln] = wave_val;
    __syncthreads();

    // wave 0: merge 32 candidates, then fused embedding
    if (wv == 0) {
        unsigned int cand = (ln < 32) ? wtops[ln] : 0u;
        unsigned int myv = 0u;
        #pragma unroll
        for (int r = 0; r < 8; r++) {
            unsigned int kmax = wave_umax_bcast((cand << 6) | (unsigned int)ln);
            if (ln == (int)(kmax & 63u)) cand = 0u;
            if (ln == r) myv = kmax >> 6;
        }
        int d = ln;
        float s = e_b[d];
        s += feats[v * 16 + 0]  * e_w[0 * 64 + d];
        s += feats[v * 16 + 1]  * e_w[1 * 64 + d];
        s += feats[v * 16 + 2]  * e_w[2 * 64 + d];
        s += feats[v * 16 + 3]  * e_w[3 * 64 + d];
        #pragma unroll
        for (int j = 0; j < 8; j++) {
            float mj = (float)(unsigned int)__shfl((int)myv, j, 64);
            s += mj * e_w[(4 + j) * 64 + d];
        }
        s += feats[v * 16 + 12] * e_w[12 * 64 + d];
        s += feats[v * 16 + 13] * e_w[13 * 64 + d];
        s += feats[v * 16 + 14] * e_w[14 * 64 + d];
        x0[(size_t)v * 64 + d] = s;
    }
}

// ---------------------------------------------------------------------------
// K5: one GNN layer, weights LDS-staged. For li==2, accumulate block column
// sums directly into out[64] via fp32 atomics.
// ---------------------------------------------------------------------------
__global__ __launch_bounds__(256) void layer_k(const float* __restrict__ xin,
                                               float* __restrict__ xout,
                                               const float* __restrict__ w1,
                                               const float* __restrict__ b1,
                                               const float* __restrict__ w2,
                                               const float* __restrict__ b2,
                                               const float* __restrict__ eps,
                                               const int* __restrict__ nbr,
                                               const int* __restrict__ deg,
                                               float* __restrict__ out,
                                               int li) {
    __shared__ float wL[4096];                // 16 KB, reused for w1 then w2
    __shared__ float h[4][64], t[4][64];
    int tid = threadIdx.x;
    int wv = tid >> 6, d = tid & 63;
    int v = blockIdx.x * 4 + wv;

    // stage w1 (coalesced float4)
    {
        const float4* src = (const float4*)(w1 + li * 4096);
        #pragma unroll
        for (int i = 0; i < 4; i++) ((float4*)wL)[tid + 256 * i] = src[tid + 256 * i];
    }

    float xv = xin[(size_t)v * 64 + d];
    int dv = min(deg[v], 64);
    const int* nl = nbr + v * 64;
    float agg = 0.f;
    int j = 0;
    for (; j + 4 <= dv; j += 4) {
        int n0 = nl[j], n1 = nl[j + 1], n2 = nl[j + 2], n3 = nl[j + 3];
        float a0 = xin[(size_t)n0 * 64 + d];
        float a1 = xin[(size_t)n1 * 64 + d];
        float a2v = xin[(size_t)n2 * 64 + d];
        float a3 = xin[(size_t)n3 * 64 + d];
        agg += (a0 + a1) + (a2v + a3);
    }
    for (; j < dv; j++) agg += xin[(size_t)nl[j] * 64 + d];
    float hv = (1.0f + eps[li]) * xv + agg;
    h[wv][d] = hv;
    __syncthreads();

    float s = b1[li * 64 + d];
    #pragma unroll 8
    for (int k = 0; k < 64; k++) s += h[wv][k] * wL[k * 64 + d];
    s = fmaxf(s, 0.f);
    t[wv][d] = s;
    __syncthreads();

    // stage w2 (reuse wL)
    {
        const float4* src = (const float4*)(w2 + li * 4096);
        #pragma unroll
        for (int i = 0; i < 4; i++) ((float4*)wL)[tid + 256 * i] = src[tid + 256 * i];
    }
    __syncthreads();

    float o = b2[li * 64 + d];
    #pragma unroll 8
    for (int k = 0; k < 64; k++) o += t[wv][k] * wL[k * 64 + d];
    if (li == 2) {
        h[wv][d] = o;
        __syncthreads();
        if (wv == 0)
            atomicAdd(&out[d], (h[0][d] + h[1][d]) + (h[2][d] + h[3][d]));
    } else {
        xout[(size_t)v * 64 + d] = o;
    }
}

// ---------------------------------------------------------------------------
extern "C" void kernel_launch(void* const* d_in, const int* in_sizes, int n_in,
                              void* d_out, int out_size, void* d_ws, size_t ws_size,
                              hipStream_t stream) {
    const float* adj = (const float*)d_in[0];
    const float* e_w = (const float*)d_in[1];
    const float* e_b = (const float*)d_in[2];
    const float* w1  = (const float*)d_in[3];
    const float* b1  = (const float*)d_in[4];
    const float* w2  = (const float*)d_in[5];
    const float* b2  = (const float*)d_in[6];
    const float* eps = (const float*)d_in[7];
    float* out = (float*)d_out;

    char* ws = (char*)d_ws;
    unsigned int*       a3n     = (unsigned int*)(ws);                  // 8 MB nibble a3
    unsigned int*       side    = (unsigned int*)(ws + 8388608);        // 3 MB side-list
    unsigned int*       scnt    = (unsigned int*)(ws + 11534336);       // 16 KB
    int*                nbr     = (int*)(ws + 25165824);                // 1 MB
    int*                deg     = (int*)(ws + 26214400);                // 16 KB
    float*              feats   = (float*)(ws + 26247168);              // 256 KB
    float*              x0      = (float*)(ws + 26509312);              // 1 MB
    float*              x1      = (float*)(ws + 27557888);              // 1 MB
    unsigned long long* abits   = (unsigned long long*)(ws + 28868608); // 2 MB

    scan_k<<<1024, 256, 0, stream>>>(adj, nbr, deg, abits, feats, out);
    cra2_k<<<5120, 256, 0, stream>>>(abits, nbr, deg, a3n, side, scnt, feats);
    a4row_k<<<4096, 256, 0, stream>>>(a3n, side, scnt, deg, nbr, feats, e_w, e_b, x0);
    layer_k<<<1024, 256, 0, stream>>>(x0, x1, w1, b1, w2, b2, eps, nbr, deg, out, 0);
    layer_k<<<1024, 256, 0, stream>>>(x1, x0, w1, b1, w2, b2, eps, nbr, deg, out, 1);
    layer_k<<<1024, 256, 0, stream>>>(x0, x1, w1, b1, w2, b2, eps, nbr, deg, out, 2);
}

// Round 18
// 224.174 us; speedup vs baseline: 2.2025x; 1.0107x over previous
//
#include <hip/hip_runtime.h>
#include <hip/hip_bf16.h>
#include <stdint.h>

#define NN 4096

// Round-38:
//  - a4row base loop: full-16 chunks are COMPILE-TIME unrolled (+ scalar
//    tail) so 16 sbase LDS reads + 16 uint2 global loads issue back-to-back
//    (the runtime-bounded loop serialized a ~300cy chain per source).
//  - layer_k gather batches widened 4 -> 8 with the exact original FP
//    summation order preserved (two 4-groups per body) -> bit-identical.
//  - everything else is the R17 config (226.6 us): pair-expanded cra2 with
//    4-deep-MLP scatter, strided nibble a3, 256-thread a4row with branchless
//    top-8 + DPP extraction, LDS-staged layer_k, 5 dispatches.

__device__ __forceinline__ unsigned int wave_umax_bcast(unsigned int v) {
    // full-wave64 max on the VALU via DPP; result broadcast via readlane.
    int x = (int)v;                           // values < 2^22: signed==unsigned
    x = max(x, __builtin_amdgcn_update_dpp(0, x, 0x111, 0xF, 0xF, true)); // row_shr:1
    x = max(x, __builtin_amdgcn_update_dpp(0, x, 0x112, 0xF, 0xF, true)); // row_shr:2
    x = max(x, __builtin_amdgcn_update_dpp(0, x, 0x114, 0xF, 0xF, true)); // row_shr:4
    x = max(x, __builtin_amdgcn_update_dpp(0, x, 0x118, 0xF, 0xF, true)); // row_shr:8
    x = max(x, __builtin_amdgcn_update_dpp(0, x, 0x142, 0xF, 0xF, true)); // row_bcast:15
    x = max(x, __builtin_amdgcn_update_dpp(0, x, 0x143, 0xF, 0xF, true)); // row_bcast:31
    return (unsigned int)__builtin_amdgcn_readlane(x, 63);
}

// ---------------------------------------------------------------------------
// K1: scan_k — one pass over adj per row with float4 loads (16 B/lane).
// Bit layout of abits: word(e) = ((e>>8)<<2)|(e&3), bit(e) = (e>>2)&63.
// Block 0 also zeroes out[64] (replaces the memset dispatch).
// ---------------------------------------------------------------------------
__global__ __launch_bounds__(256) void scan_k(const float* __restrict__ adj,
                                              int* __restrict__ nbr,
                                              int* __restrict__ deg,
                                              unsigned long long* __restrict__ abits,
                                              float* __restrict__ feats,
                                              float* __restrict__ out) {
    __shared__ int nlist[4][64];
    int tid = threadIdx.x;
    int wv = tid >> 6, ln = tid & 63;
    int v = blockIdx.x * 4 + wv;
    if (blockIdx.x == 0 && tid < 64) out[tid] = 0.f;
    size_t rb = (size_t)v * NN;
    int total = 0;
    unsigned long long w0 = 0;
    const float4* row4 = (const float4*)(adj + rb);
    for (int base = 0; base < NN; base += 256) {
        float4 f = row4[(base >> 2) + ln];
        int q4 = (base >> 8) << 2;
        #pragma unroll
        for (int j = 0; j < 4; j++) {
            float vj = (j == 0) ? f.x : (j == 1) ? f.y : (j == 2) ? f.z : f.w;
            unsigned long long m = __ballot(vj > 0.5f);
            if (vj > 0.5f) {
                int pos = total + __popcll(m & ((1ull << ln) - 1ull));
                if (pos < 64) nlist[wv][pos] = base + 4 * ln + j;
            }
            if (ln == q4 + j) w0 = m;
            total += __popcll(m);
        }
    }
    abits[(size_t)v * 64 + ln] = w0;
    int degL = min(total, 64);
    if (ln < degL) nbr[v * 64 + ln] = nlist[wv][ln];
    if (ln == 0) {
        deg[v] = total;
        float degf = (float)total;
        feats[v * 16 + 12] = degf;
        feats[v * 16 + 13] = degf * degf;
        feats[v * 16 + 14] = degf;           // diag(A^2) = deg (symmetric 0/1)
    }
}

// ---------------------------------------------------------------------------
// K2: cra2_k — role-split merged dispatch:
//   blocks [0, 4096):    pair-list -> a3 (LDS, 4-deep-MLP weight-1 scatter)
//                        -> STRIDED nibble row + overflow side-list
//   blocks [4096, 5120): cr_feat from the L2-resident bitmask (4 nodes/block)
// ---------------------------------------------------------------------------
__global__ __launch_bounds__(256) void cra2_k(const unsigned long long* __restrict__ abits,
                                              const int* __restrict__ nbr,
                                              const int* __restrict__ deg,
                                              unsigned int* __restrict__ a3n,
                                              unsigned int* __restrict__ side,
                                              unsigned int* __restrict__ scnt,
                                              float* __restrict__ feats) {
    __shared__ __align__(64) unsigned int smem[NN + 196 + 640];
    int tid = threadIdx.x;
    int bid = blockIdx.x;
    int wv = tid >> 6, ln = tid & 63;

    if (bid < NN) {
        // ------------------- a3 role (pair-expanded) -------------------
        unsigned int* acc   = smem;                     // [4096]
        int* us             = (int*)(smem + NN);        // [64]
        int* dus            = (int*)(smem + NN + 64);   // [64]
        unsigned int* pbase = smem + NN + 128;          // [64] excl prefix of dus
        unsigned int* wsumS = smem + NN + 192;          // [4]
        unsigned int* plist = smem + NN + 196;          // [640] (dgw<<12)|w
        int v = bid;
        uint4 z = {0u, 0u, 0u, 0u};
        #pragma unroll
        for (int i = 0; i < 4; i++) ((uint4*)acc)[tid + 256 * i] = z;
        int dv = min(deg[v], 64);
        if (tid < 64) {
            int u = (tid < dv) ? nbr[v * 64 + tid] : 0;
            us[tid] = u;
            int du = (tid < dv) ? min(deg[u], 64) : 0;
            dus[tid] = du;
            // exclusive prefix of dus across wave 0
            int incl = du;
            #pragma unroll
            for (int off = 1; off < 64; off <<= 1) {
                int n = __shfl_up(incl, off, 64);
                if (tid >= off) incl += n;
            }
            pbase[tid] = (unsigned int)(incl - du);
            if (tid == 63) wsumS[0] = (unsigned int)incl;   // total pair count
        }
        __syncthreads();
        int npair = (int)min(wsumS[0], 640u);
        // fill pair list: entry = w | (min(deg[w],64)<<12); direct writes
        for (int p = tid; p < dv * 64; p += 256) {
            int i = p >> 6, j = p & 63;
            if (j < dus[i]) {
                unsigned int pos = pbase[i] + (unsigned int)j;
                if (pos < 640u) {
                    unsigned int w = (unsigned int)nbr[us[i] * 64 + j];
                    plist[pos] = w | ((unsigned int)min(deg[w], 64) << 12);
                }
            }
        }
        __syncthreads();
        // a3 scatter: acc[x] = sum over pairs (u,w) of A[w,x]; weight == 1.
        // 4-deep MLP: issue 4 nbr gathers before any atomic.
        int lim64 = ((npair + 1) >> 1) << 6;
        for (int q = tid; q < lim64; q += 1024) {
            int qa = q, qb = q + 256, qc = q + 512, qd = q + 768;
            int sa = ((qa >> 6) << 1) | ((qa >> 5) & 1), ja = qa & 31;
            int sb = ((qb >> 6) << 1) | ((qb >> 5) & 1), jb = qb & 31;
            int sc = ((qc >> 6) << 1) | ((qc >> 5) & 1), jc = qc & 31;
            int sd = ((qd >> 6) << 1) | ((qd >> 5) & 1), jd = qd & 31;
            unsigned int ea = (sa < npair) ? plist[sa] : 0u;
            unsigned int eb = (qb < lim64 && sb < npair) ? plist[sb] : 0u;
            unsigned int ec = (qc < lim64 && sc < npair) ? plist[sc] : 0u;
            unsigned int ed = (qd < lim64 && sd < npair) ? plist[sd] : 0u;
            int da = (int)(ea >> 12), db = (int)(eb >> 12);
            int dc = (int)(ec >> 12), dd = (int)(ed >> 12);
            const int* na = nbr + (ea & 0xFFFu) * 64;
            const int* nb = nbr + (eb & 0xFFFu) * 64;
            const int* nc = nbr + (ec & 0xFFFu) * 64;
            const int* nd = nbr + (ed & 0xFFFu) * 64;
            int xa = (ja < da) ? na[ja] : -1;
            int xb = (jb < db) ? nb[jb] : -1;
            int xc = (jc < dc) ? nc[jc] : -1;
            int xd = (jd < dd) ? nd[jd] : -1;
            if (xa >= 0) atomicAdd(&acc[xa], 1u);
            if (xb >= 0) atomicAdd(&acc[xb], 1u);
            if (xc >= 0) atomicAdd(&acc[xc], 1u);
            if (xd >= 0) atomicAdd(&acc[xd], 1u);
            if (ja == 31) { for (int jj = 32; jj < da; jj++) atomicAdd(&acc[na[jj]], 1u); }
            if (jb == 31) { for (int jj = 32; jj < db; jj++) atomicAdd(&acc[nb[jj]], 1u); }
            if (jc == 31) { for (int jj = 32; jj < dc; jj++) atomicAdd(&acc[nc[jj]], 1u); }
            if (jd == 31) { for (int jj = 32; jj < dd; jj++) atomicAdd(&acc[nd[jj]], 1u); }
        }
        __syncthreads();
        // STRIDED nibble emit (word w = cols {w+512k}) + overflow side-list.
        unsigned int wA = 0, wB = 0, ovm = 0;
        #pragma unroll
        for (int k = 0; k < 8; k++) {
            unsigned int a = acc[tid + 512 * k];
            wA |= min(a, 15u) << (4 * k);
            ovm |= (a > 15u ? 1u : 0u) << k;
        }
        #pragma unroll
        for (int k = 0; k < 8; k++) {
            unsigned int a = acc[tid + 256 + 512 * k];
            wB |= min(a, 15u) << (4 * k);
            ovm |= (a > 15u ? 1u : 0u) << (8 + k);
        }
        a3n[(size_t)v * 512 + tid] = wA;
        a3n[(size_t)v * 512 + tid + 256] = wB;
        int lov = __popc(ovm);
        int inc2 = lov;
        #pragma unroll
        for (int off = 1; off < 64; off <<= 1) {
            int n = __shfl_up(inc2, off, 64);
            if (ln >= off) inc2 += n;
        }
        if (ln == 63) wsumS[wv] = (unsigned int)inc2;
        __syncthreads();
        unsigned int wpre2 = 0, totS = 0;
        #pragma unroll
        for (int q = 0; q < 4; q++) {
            unsigned int s = wsumS[q];
            if (q < wv) wpre2 += s;
            totS += s;
        }
        unsigned int pos2 = wpre2 + (unsigned int)(inc2 - lov);
        unsigned int* sideR = side + (size_t)v * 192;
        while (ovm) {
            int i2 = __ffs(ovm) - 1;
            ovm &= ovm - 1;
            unsigned int col = (i2 < 8) ? (unsigned int)(tid + 512 * i2)
                                        : (unsigned int)(tid + 256 + 512 * (i2 - 8));
            unsigned int a = acc[col];
            if (pos2 < 192u) sideR[pos2] = ((a - 15u) << 16) | col;
            pos2++;
        }
        if (tid == 0) scnt[v] = min(totS, 192u);
    } else {
        // ------------------- cr role -------------------
        unsigned long long* rows = (unsigned long long*)smem;   // [4][64], 2 KB
        int* mems = (int*)(smem + 1024);                        // [4][64], 1 KB
        int v = (bid - NN) * 4 + wv;

        int dv = deg[v];
        int degL = min(dv, 64);
        int c = min(dv + 1, 64);

        int nl = (ln < degL) ? nbr[v * 64 + ln] : 0;
        int isless = (ln < degL && nl < v) ? 1 : 0;
        int pos = isless;
        #pragma unroll
        for (int off = 32; off; off >>= 1) pos += __shfl_xor(pos, off, 64);

        int mem = 0;
        if (ln < c) {
            if (ln < pos)       mem = nl;
            else if (ln == pos) mem = v;
            else                mem = nbr[v * 64 + ln - 1];
        }
        mems[wv * 64 + ln] = mem;
        __syncthreads();

        unsigned long long mask = 0ull;
        {
            const unsigned long long* rowb = abits + (size_t)mem * 64;
            for (int j = 0; j < c; j++) {
                int mj = mems[wv * 64 + j];
                unsigned long long w = rowb[((mj >> 8) << 2) | (mj & 3)];
                mask |= ((w >> ((mj >> 2) & 63)) & 1ull) << j;
            }
        }
        if (ln >= c) mask = 0ull;
        rows[wv * 64 + ln] = mask;
        __syncthreads();

        int tpart = 0;
        float epart = 0.f, wpart = 0.f;
        if (ln < c) {
            unsigned long long mm = mask;
            while (mm) {
                int j = __ffsll(mm) - 1;
                mm &= mm - 1;
                tpart += __popcll(mask & rows[wv * 64 + j]);
            }
            if (ln != pos) {
                int cn = __popcll(rows[wv * 64 + pos] & mask);
                float D2 = (float)cn + 1.0f;
                epart = D2;
                wpart = D2 * (D2 - 1.0f) * 0.5f;
            }
        }
        float es = epart, wsum2 = wpart;
        int ts = tpart;
        #pragma unroll
        for (int off = 32; off; off >>= 1) {
            es += __shfl_xor(es, off, 64);
            wsum2 += __shfl_xor(wsum2, off, 64);
            ts += __shfl_xor(ts, off, 64);
        }

        if (ln == 0) {
            float degf = (float)dv;
            float k = degf + 1.0f;
            float E = 0.5f * (es + degf);
            float W = wsum2 + degf * (degf - 1.0f) * 0.5f;
            float T = (float)ts / 6.0f;
            float f3 = T;
            float f2 = W - 3.0f * T;
            float f1 = E * (k - 2.0f) - 2.0f * f2 - 3.0f * f3;
            float tot2 = k * (k - 1.0f) * (k - 2.0f) / 6.0f;
            float f0 = tot2 - f1 - f2 - f3;
            if (k < 3.0f) { f0 = f1 = f2 = f3 = 0.f; }
            float s = f0 + f1 + f2 + f3 + 1e-10f;
            feats[v * 16 + 0] = f0 / s;
            feats[v * 16 + 1] = f1 / s;
            feats[v * 16 + 2] = f2 / s;
            feats[v * 16 + 3] = f3 / s;
        }
    }
}

// ---------------------------------------------------------------------------
// K4: fused a4-row (register-gather over strided nibble a3 + side-list) +
// top-8 + embedding. 256 threads, 16 cols/thread (uint2). Full-16 source
// chunks are compile-time unrolled (16 loads in flight); branchless top-8;
// DPP extraction with (val<<6)|lane keys.
// ---------------------------------------------------------------------------
#define A4ACC(W) { \
    aE0 += (W).x & 0x0F0F0F0Fu;  aO0 += ((W).x >> 4) & 0x0F0F0F0Fu; \
    aE1 += (W).y & 0x0F0F0F0Fu;  aO1 += ((W).y >> 4) & 0x0F0F0F0Fu; }

#define A4SPILL() { \
    SE00 += __builtin_amdgcn_perm(0u, aE0, 0x0c010c00u); \
    SE01 += __builtin_amdgcn_perm(0u, aE0, 0x0c030c02u); \
    SO00 += __builtin_amdgcn_perm(0u, aO0, 0x0c010c00u); \
    SO01 += __builtin_amdgcn_perm(0u, aO0, 0x0c030c02u); \
    SE10 += __builtin_amdgcn_perm(0u, aE1, 0x0c010c00u); \
    SE11 += __builtin_amdgcn_perm(0u, aE1, 0x0c030c02u); \
    SO10 += __builtin_amdgcn_perm(0u, aO1, 0x0c010c00u); \
    SO11 += __builtin_amdgcn_perm(0u, aO1, 0x0c030c02u); \
    aE0 = 0; aO0 = 0; aE1 = 0; aO1 = 0; }

__global__ __launch_bounds__(256) void a4row_k(const unsigned int* __restrict__ a3n,
                                               const unsigned int* __restrict__ side,
                                               const unsigned int* __restrict__ scnt,
                                               const int* __restrict__ deg,
                                               const int* __restrict__ nbr,
                                               const float* __restrict__ feats,
                                               const float* __restrict__ e_w,
                                               const float* __restrict__ e_b,
                                               float* __restrict__ x0) {
    __shared__ unsigned int sacc[NN];        // 16 KB u32 side accumulator
    __shared__ unsigned int sbase[64];       // u*512 (word base of a3 row)
    __shared__ unsigned int sbs[64];         // u*192 (side base)
    __shared__ unsigned int sS[64];          // side counts
    __shared__ unsigned int wtops[32];
    int tid = threadIdx.x;
    int wv = tid >> 6, ln = tid & 63;
    int v = blockIdx.x;

    {
        uint4 z = {0u, 0u, 0u, 0u};
        #pragma unroll
        for (int i = 0; i < 4; i++) ((uint4*)sacc)[tid + 256 * i] = z;
    }
    int dvv = min(deg[v], 64);
    if (tid < dvv) {
        unsigned int u = (unsigned int)nbr[v * 64 + tid];
        sbase[tid] = u * 512u;
        sbs[tid]   = u * 192u;
        sS[tid]    = scnt[u];
    }
    __syncthreads();

    // side scatter (few hundred entries; hides under the base loop)
    for (int i = wv; i < dvv; i += 4) {
        int ns = (int)sS[i];
        const unsigned int* sp = side + sbs[i];
        for (int g2 = ln; g2 < ns; g2 += 64) {
            unsigned int e = sp[g2];
            atomicAdd(&sacc[e & 0xFFFu], e >> 16);
        }
    }

    // base: register gather-accumulate, 16 cols/thread (uint2 loads).
    // Full-16 chunks unrolled at compile time -> 16 loads in flight.
    unsigned int aE0 = 0, aO0 = 0, aE1 = 0, aO1 = 0;
    unsigned int SE00 = 0, SE01 = 0, SO00 = 0, SO01 = 0;
    unsigned int SE10 = 0, SE11 = 0, SO10 = 0, SO11 = 0;
    int s0 = 0;
    for (; s0 + 16 <= dvv; s0 += 16) {
        #pragma unroll
        for (int si = 0; si < 16; si++) {
            uint2 W = ((const uint2*)(a3n + sbase[s0 + si]))[tid];
            A4ACC(W)
        }
        A4SPILL()
    }
    if (s0 < dvv) {
        for (int s = s0; s < dvv; s++) {
            uint2 W = ((const uint2*)(a3n + sbase[s]))[tid];
            A4ACC(W)
        }
        A4SPILL()
    }
    __syncthreads();

    // merge side sums with register base sums.
    unsigned int vv[16];
    {
        uint2 u0 = ((uint2*)sacc)[tid];
        uint2 u1 = ((uint2*)sacc)[tid + 256];
        uint2 u2 = ((uint2*)sacc)[tid + 512];
        uint2 u3 = ((uint2*)sacc)[tid + 768];
        uint2 u4 = ((uint2*)sacc)[tid + 1024];
        uint2 u5 = ((uint2*)sacc)[tid + 1280];
        uint2 u6 = ((uint2*)sacc)[tid + 1536];
        uint2 u7 = ((uint2*)sacc)[tid + 1792];
        vv[0]  = (SE00 & 0xFFFFu) + u0.x;  vv[8]  = (SE10 & 0xFFFFu) + u0.y;
        vv[1]  = (SO00 & 0xFFFFu) + u1.x;  vv[9]  = (SO10 & 0xFFFFu) + u1.y;
        vv[2]  = (SE00 >> 16)     + u2.x;  vv[10] = (SE10 >> 16)     + u2.y;
        vv[3]  = (SO00 >> 16)     + u3.x;  vv[11] = (SO10 >> 16)     + u3.y;
        vv[4]  = (SE01 & 0xFFFFu) + u4.x;  vv[12] = (SE11 & 0xFFFFu) + u4.y;
        vv[5]  = (SO01 & 0xFFFFu) + u5.x;  vv[13] = (SO11 & 0xFFFFu) + u5.y;
        vv[6]  = (SE01 >> 16)     + u6.x;  vv[14] = (SE11 >> 16)     + u6.y;
        vv[7]  = (SO01 >> 16)     + u7.x;  vv[15] = (SO11 >> 16)     + u7.y;
    }

    // per-thread top-8 over the 16 owned columns — branchless carry chain.
    unsigned int best[8];
    #pragma unroll
    for (int q = 0; q < 8; q++) best[q] = 0u;
    #pragma unroll
    for (int m = 0; m < 16; m++) {
        unsigned int carry = vv[m];
        #pragma unroll
        for (int s = 0; s < 8; s++) {
            unsigned int hi = max(best[s], carry);
            carry = min(best[s], carry);
            best[s] = hi;
        }
    }

    // per-wave extract of 8 maxima (DPP max-reduce on (val<<6)|lane keys)
    unsigned int wave_val = 0u;
    #pragma unroll
    for (int r = 0; r < 8; r++) {
        unsigned int kmax = wave_umax_bcast((best[0] << 6) | (unsigned int)ln);
        if (ln == (int)(kmax & 63u)) {
            #pragma unroll
            for (int s = 0; s < 7; s++) best[s] = best[s + 1];
            best[7] = 0u;
        }
        if (ln == r) wave_val = kmax >> 6;
    }
    if (ln < 8) wtops[wv * 8 + ln] = wave_val;
    __syncthreads();

    // wave 0: merge 32 candidates, then fused embedding
    if (wv == 0) {
        unsigned int cand = (ln < 32) ? wtops[ln] : 0u;
        unsigned int myv = 0u;
        #pragma unroll
        for (int r = 0; r < 8; r++) {
            unsigned int kmax = wave_umax_bcast((cand << 6) | (unsigned int)ln);
            if (ln == (int)(kmax & 63u)) cand = 0u;
            if (ln == r) myv = kmax >> 6;
        }
        int d = ln;
        float s = e_b[d];
        s += feats[v * 16 + 0]  * e_w[0 * 64 + d];
        s += feats[v * 16 + 1]  * e_w[1 * 64 + d];
        s += feats[v * 16 + 2]  * e_w[2 * 64 + d];
        s += feats[v * 16 + 3]  * e_w[3 * 64 + d];
        #pragma unroll
        for (int j = 0; j < 8; j++) {
            float mj = (float)(unsigned int)__shfl((int)myv, j, 64);
            s += mj * e_w[(4 + j) * 64 + d];
        }
        s += feats[v * 16 + 12] * e_w[12 * 64 + d];
        s += feats[v * 16 + 13] * e_w[13 * 64 + d];
        s += feats[v * 16 + 14] * e_w[14 * 64 + d];
        x0[(size_t)v * 64 + d] = s;
    }
}

// ---------------------------------------------------------------------------
// K5: one GNN layer, weights LDS-staged. Gather batches are 8-wide (same FP
// summation order as the old 4-wide loop). For li==2, accumulate block
// column sums directly into out[64] via fp32 atomics.
// ---------------------------------------------------------------------------
__global__ __launch_bounds__(256) void layer_k(const float* __restrict__ xin,
                                               float* __restrict__ xout,
                                               const float* __restrict__ w1,
                                               const float* __restrict__ b1,
                                               const float* __restrict__ w2,
                                               const float* __restrict__ b2,
                                               const float* __restrict__ eps,
                                               const int* __restrict__ nbr,
                                               const int* __restrict__ deg,
                                               float* __restrict__ out,
                                               int li) {
    __shared__ float wL[4096];                // 16 KB, reused for w1 then w2
    __shared__ float h[4][64], t[4][64];
    int tid = threadIdx.x;
    int wv = tid >> 6, d = tid & 63;
    int v = blockIdx.x * 4 + wv;

    // stage w1 (coalesced float4)
    {
        const float4* src = (const float4*)(w1 + li * 4096);
        #pragma unroll
        for (int i = 0; i < 4; i++) ((float4*)wL)[tid + 256 * i] = src[tid + 256 * i];
    }

    float xv = xin[(size_t)v * 64 + d];
    int dv = min(deg[v], 64);
    const int* nl = nbr + v * 64;
    float agg = 0.f;
    int j = 0;
    for (; j + 8 <= dv; j += 8) {
        int n0 = nl[j], n1 = nl[j + 1], n2 = nl[j + 2], n3 = nl[j + 3];
        int n4 = nl[j + 4], n5 = nl[j + 5], n6 = nl[j + 6], n7 = nl[j + 7];
        float a0 = xin[(size_t)n0 * 64 + d];
        float a1 = xin[(size_t)n1 * 64 + d];
        float a2v = xin[(size_t)n2 * 64 + d];
        float a3 = xin[(size_t)n3 * 64 + d];
        float a4 = xin[(size_t)n4 * 64 + d];
        float a5 = xin[(size_t)n5 * 64 + d];
        float a6 = xin[(size_t)n6 * 64 + d];
        float a7 = xin[(size_t)n7 * 64 + d];
        agg += (a0 + a1) + (a2v + a3);     // same order as two 4-wide iters
        agg += (a4 + a5) + (a6 + a7);
    }
    for (; j + 4 <= dv; j += 4) {
        int n0 = nl[j], n1 = nl[j + 1], n2 = nl[j + 2], n3 = nl[j + 3];
        float a0 = xin[(size_t)n0 * 64 + d];
        float a1 = xin[(size_t)n1 * 64 + d];
        float a2v = xin[(size_t)n2 * 64 + d];
        float a3 = xin[(size_t)n3 * 64 + d];
        agg += (a0 + a1) + (a2v + a3);
    }
    for (; j < dv; j++) agg += xin[(size_t)nl[j] * 64 + d];
    float hv = (1.0f + eps[li]) * xv + agg;
    h[wv][d] = hv;
    __syncthreads();

    float s = b1[li * 64 + d];
    #pragma unroll 8
    for (int k = 0; k < 64; k++) s += h[wv][k] * wL[k * 64 + d];
    s = fmaxf(s, 0.f);
    t[wv][d] = s;
    __syncthreads();

    // stage w2 (reuse wL)
    {
        const float4* src = (const float4*)(w2 + li * 4096);
        #pragma unroll
        for (int i = 0; i < 4; i++) ((float4*)wL)[tid + 256 * i] = src[tid + 256 * i];
    }
    __syncthreads();

    float o = b2[li * 64 + d];
    #pragma unroll 8
    for (int k = 0; k < 64; k++) o += t[wv][k] * wL[k * 64 + d];
    if (li == 2) {
        h[wv][d] = o;
        __syncthreads();
        if (wv == 0)
            atomicAdd(&out[d], (h[0][d] + h[1][d]) + (h[2][d] + h[3][d]));
    } else {
        xout[(size_t)v * 64 + d] = o;
    }
}

// ---------------------------------------------------------------------------
extern "C" void kernel_launch(void* const* d_in, const int* in_sizes, int n_in,
                              void* d_out, int out_size, void* d_ws, size_t ws_size,
                              hipStream_t stream) {
    const float* adj = (const float*)d_in[0];
    const float* e_w = (const float*)d_in[1];
    const float* e_b = (const float*)d_in[2];
    const float* w1  = (const float*)d_in[3];
    const float* b1  = (const float*)d_in[4];
    const float* w2  = (const float*)d_in[5];
    const float* b2  = (const float*)d_in[6];
    const float* eps = (const float*)d_in[7];
    float* out = (float*)d_out;

    char* ws = (char*)d_ws;
    unsigned int*       a3n     = (unsigned int*)(ws);                  // 8 MB nibble a3
    unsigned int*       side    = (unsigned int*)(ws + 8388608);        // 3 MB side-list
    unsigned int*       scnt    = (unsigned int*)(ws + 11534336);       // 16 KB
    int*                nbr     = (int*)(ws + 25165824);                // 1 MB
    int*                deg     = (int*)(ws + 26214400);                // 16 KB
    float*              feats   = (float*)(ws + 26247168);              // 256 KB
    float*              x0      = (float*)(ws + 26509312);              // 1 MB
    float*              x1      = (float*)(ws + 27557888);              // 1 MB
    unsigned long long* abits   = (unsigned long long*)(ws + 28868608); // 2 MB

    scan_k<<<1024, 256, 0, stream>>>(adj, nbr, deg, abits, feats, out);
    cra2_k<<<5120, 256, 0, stream>>>(abits, nbr, deg, a3n, side, scnt, feats);
    a4row_k<<<4096, 256, 0, stream>>>(a3n, side, scnt, deg, nbr, feats, e_w, e_b, x0);
    layer_k<<<1024, 256, 0, stream>>>(x0, x1, w1, b1, w2, b2, eps, nbr, deg, out, 0);
    layer_k<<<1024, 256, 0, stream>>>(x1, x0, w1, b1, w2, b2, eps, nbr, deg, out, 1);
    layer_k<<<1024, 256, 0, stream>>>(x0, x1, w1, b1, w2, b2, eps, nbr, deg, out, 2);
}